// Round 9
// baseline (709.510 us; speedup 1.0000x reference)
//
#include <hip/hip_runtime.h>
#include <math.h>

#define BB 2
#define NN 16384
#define MM 4096
#define C_IN 32
#define D_DIM 64
#define H_DIM 32
#define KNB 16
#define EPSV 1e-5f
#define FLT_BIG 3.0e38f
#define CAPK 128
#define GG 32
#define G3 (GG * GG * GG)
#define LO_BOUND (-5.0f)
#define H_CELL (10.0f / (float)GG)
#define INV_H ((float)GG / 10.0f)

// stats layout (floats)
#define SPOS_SUM 0
#define SPOS_SQ 32
#define SFEAT_SUM 64
#define SFEAT_SQ 96
#define SSC1_SUM 128
#define SSC1_SQ 192
#define SSC2_SUM 256
#define SSC2_SQ 320
#define SOUT_SUM 384
#define SOUT_SQ 448
#define STATS_LEN 512
#define PA_W 384
#define PB_W 128
#define NBLK (BB * MM / 4)

typedef float f32x2 __attribute__((ext_vector_type(2)));

__device__ __forceinline__ f32x2 mk2_r25(float a, float b) {
    f32x2 r; r.x = a; r.y = b; return r;
}

__device__ __forceinline__ int clampi_r25(int v, int lo, int hi) {
    return v < lo ? lo : (v > hi ? hi : v);
}

__device__ __forceinline__ int cell_of_r25(float v) {
    int c = (int)floorf((v - LO_BOUND) * INV_H);
    return clampi_r25(c, 0, GG - 1);
}

// ---------------- prep: transpose + xyz4 + outputs 0&2 + stats/cellcnt zero ----------------
__global__ __launch_bounds__(256) void prep_r25(const float* __restrict__ feats,
                                                const float* __restrict__ xyz,
                                                const int* __restrict__ sample_idx,
                                                float* __restrict__ featsT,
                                                float* __restrict__ xyz4,
                                                float* __restrict__ stats,
                                                int* __restrict__ cellcnt,
                                                float* __restrict__ out) {
    __shared__ float tile[C_IN][65];
    const int tid = threadIdx.x;
    const int b = blockIdx.x >> 8;
    const int n0 = (blockIdx.x & 255) * 64;
#pragma unroll
    for (int it = 0; it < 8; ++it) {
        int c = (tid >> 6) + 4 * it;
        int n = tid & 63;
        tile[c][n] = feats[((size_t)b * C_IN + c) * NN + n0 + n];
    }
    int e = blockIdx.x * 256 + tid;
    if (e < STATS_LEN) stats[e] = 0.f;
    if (e < BB * G3) cellcnt[e] = 0;
    if (e < BB * NN) {
        float x = xyz[e * 3 + 0], y = xyz[e * 3 + 1], z = xyz[e * 3 + 2];
        xyz4[e * 4 + 0] = x;
        xyz4[e * 4 + 1] = y;
        xyz4[e * 4 + 2] = z;
        xyz4[e * 4 + 3] = x * x + y * y + z * z;
    }
    if (e < BB * MM) {
        int bb2 = e >> 12;
        int sidx = clampi_r25(sample_idx[e], 0, NN - 1);
        const float* p = xyz + (size_t)(bb2 * NN + sidx) * 3;
        out[e * 3 + 0] = p[0];
        out[e * 3 + 1] = p[1];
        out[e * 3 + 2] = p[2];
        out[BB * MM * 3 + BB * D_DIM * MM + e] = (float)sample_idx[e];
    }
    __syncthreads();
#pragma unroll
    for (int it = 0; it < 8; ++it) {
        int c = tid & 31;
        int nn = (tid >> 5) + 8 * it;
        featsT[((size_t)b * NN + n0 + nn) * C_IN + c] = tile[c][nn];
    }
}

// ---------------- hist: count points per cell ----------------
__global__ __launch_bounds__(256) void hist_r25(const float* __restrict__ xyz,
                                                int* __restrict__ cellcnt) {
    int e = blockIdx.x * 256 + threadIdx.x;
    if (e >= BB * NN) return;
    int b = e >> 14;
    float x = xyz[e * 3 + 0], y = xyz[e * 3 + 1], z = xyz[e * 3 + 2];
    int cid = (cell_of_r25(z) * GG + cell_of_r25(y)) * GG + cell_of_r25(x);
    atomicAdd(&cellcnt[b * G3 + cid], 1);
}

// ---------------- scan: per-batch exclusive prefix over 32768 cells ----------------
__global__ __launch_bounds__(256) void scan_r25(const int* __restrict__ cellcnt,
                                                int* __restrict__ cellstart,
                                                int* __restrict__ cursor) {
    __shared__ int psum[256];
    const int b = blockIdx.x;
    const int tid = threadIdx.x;
    const int cbase = b * G3;
    const int sbase = b * (G3 + 1);
    int s = 0;
#pragma unroll 1
    for (int i = tid * 128; i < (tid + 1) * 128; ++i) s += cellcnt[cbase + i];
    psum[tid] = s;
    __syncthreads();
    // Hillis-Steele inclusive scan over 256 partials
    for (int off = 1; off < 256; off <<= 1) {
        int t = (tid >= off) ? psum[tid - off] : 0;
        __syncthreads();
        psum[tid] += t;
        __syncthreads();
    }
    int run = (tid == 0) ? 0 : psum[tid - 1];
#pragma unroll 1
    for (int i = tid * 128; i < (tid + 1) * 128; ++i) {
        cellstart[sbase + i] = run;
        cursor[cbase + i] = run;
        run += cellcnt[cbase + i];
    }
    if (tid == 255) cellstart[sbase + G3] = run;
}

// ---------------- scatter: reorder points cell-contiguous, idx in .w ----------------
__global__ __launch_bounds__(256) void scatter_r25(const float* __restrict__ xyz,
                                                   int* __restrict__ cursor,
                                                   float* __restrict__ xyzr) {
    int e = blockIdx.x * 256 + threadIdx.x;
    if (e >= BB * NN) return;
    int b = e >> 14;
    int n = e & (NN - 1);
    float x = xyz[e * 3 + 0], y = xyz[e * 3 + 1], z = xyz[e * 3 + 2];
    int cid = (cell_of_r25(z) * GG + cell_of_r25(y)) * GG + cell_of_r25(x);
    int pos = atomicAdd(&cursor[b * G3 + cid], 1);
    float4* dst = reinterpret_cast<float4*>(xyzr) + (size_t)b * NN + pos;
    float4 v;
    v.x = x; v.y = y; v.z = z; v.w = __int_as_float(n);
    *dst = v;
}

// whole-batch exact scan fallback (only if candidate buffer overflows — ~never)
__device__ void knn_fullN_r25(const float* __restrict__ base4,
                              float qx, float qy, float qz, int lane,
                              int* __restrict__ outi) {
    float d2v[KNB]; int iv[KNB];
#pragma unroll
    for (int i = 0; i < KNB; i++) { d2v[i] = FLT_BIG; iv[i] = 0x7FFFFFFF; }
    float curmax = FLT_BIG; int amax = 0;
    for (int n = lane; n < NN; n += 64) {
        const float4 p = *reinterpret_cast<const float4*>(base4 + (size_t)n * 4);
        float dx = qx - p.x, dy = qy - p.y, dz = qz - p.z;
        float d2 = dx * dx;
        d2 = fmaf(dy, dy, d2);
        d2 = fmaf(dz, dz, d2);
        if (d2 < curmax) {
#pragma unroll
            for (int i = 0; i < KNB; i++)
                if (i == amax) { d2v[i] = d2; iv[i] = n; }
            curmax = d2v[0]; amax = 0;
#pragma unroll
            for (int i = 1; i < KNB; i++)
                if (d2v[i] > curmax) { curmax = d2v[i]; amax = i; }
        }
    }
#pragma unroll
    for (int i = 0; i < KNB; i++) {
#pragma unroll
        for (int j = 0; j < KNB - 1; j++) {
            bool sw = (d2v[j] > d2v[j + 1]) ||
                      (d2v[j] == d2v[j + 1] && iv[j] > iv[j + 1]);
            if (sw) {
                float td = d2v[j]; d2v[j] = d2v[j + 1]; d2v[j + 1] = td;
                int   ti = iv[j];  iv[j]  = iv[j + 1];  iv[j + 1]  = ti;
            }
        }
    }
#pragma unroll 1
    for (int r = 0; r < KNB; r++) {
        float cv = d2v[0]; int cid = iv[0]; int ml = lane;
#pragma unroll
        for (int off = 32; off > 0; off >>= 1) {
            float ov = __shfl_xor(cv, off);
            int   oid = __shfl_xor(cid, off);
            int   ol = __shfl_xor(ml, off);
            bool take = (ov < cv) || (ov == cv && oid < cid);
            cv = take ? ov : cv; cid = take ? oid : cid; ml = take ? ol : ml;
        }
        if (lane == r) outi[r] = cid;
        if (lane == ml) {
#pragma unroll
            for (int i = 0; i < KNB - 1; i++) { d2v[i] = d2v[i + 1]; iv[i] = iv[i + 1]; }
            d2v[KNB - 1] = FLT_BIG; iv[KNB - 1] = 0x7FFFFFFF;
        }
    }
}

// ---------------- knnq: exact grid-binned KNN, one wave per query ----------------
__global__ __launch_bounds__(256) void knnq_r25(const float* __restrict__ xyz4,
                                                const int* __restrict__ sample_idx,
                                                const int* __restrict__ cellstart,
                                                const float* __restrict__ xyzr,
                                                int* __restrict__ cand_i) {
    __shared__ float bufd[4][CAPK];
    __shared__ int   bufi[4][CAPK];
    const int tid = threadIdx.x;
    const int w = tid >> 6, lane = tid & 63;
    const int q = blockIdx.x * 4 + w;
    const int b = q >> 12;
    const int sidx = clampi_r25(sample_idx[q], 0, NN - 1);
    const float* base4 = xyz4 + (size_t)b * NN * 4;
    const float qx = base4[(size_t)sidx * 4 + 0];
    const float qy = base4[(size_t)sidx * 4 + 1];
    const float qz = base4[(size_t)sidx * 4 + 2];
    const int cx = cell_of_r25(qx), cy = cell_of_r25(qy), cz = cell_of_r25(qz);
    const int* cs = cellstart + (size_t)b * (G3 + 1);
    const float4* pts = reinterpret_cast<const float4*>(xyzr) + (size_t)b * NN;

    // --- seed radius: grow cube until it holds >= 16 points (cheap: prefix diffs)
    int R = 0;
#pragma unroll 1
    for (;; ++R) {
        int c = 0;
#pragma unroll 1
        for (int dz = -R; dz <= R; ++dz) {
            int z = cz + dz;
            if (z < 0 || z >= GG) continue;
#pragma unroll 1
            for (int dy = -R; dy <= R; ++dy) {
                int y = cy + dy;
                if (y < 0 || y >= GG) continue;
                int x0 = max(0, cx - R), x1 = min(GG - 1, cx + R);
                int base = (z * GG + y) * GG;
                c += cs[base + x1 + 1] - cs[base + x0];
            }
        }
        if (c >= KNB || R >= GG) break;
    }
    // --- seed bound S16: 16th-smallest of 64 lane-mins over cube(R).
    // >=16 distinct points (the 16 lanes' min points) have d2 <= S16 => valid
    // upper bound on the true 16th-NN distance. If <16 lanes valid, grow.
    float S16;
#pragma unroll 1
    for (;; ++R) {
        float md = FLT_BIG;
#pragma unroll 1
        for (int dz = -R; dz <= R; ++dz) {
            int z = cz + dz;
            if (z < 0 || z >= GG) continue;
#pragma unroll 1
            for (int dy = -R; dy <= R; ++dy) {
                int y = cy + dy;
                if (y < 0 || y >= GG) continue;
                int x0 = max(0, cx - R), x1 = min(GG - 1, cx + R);
                int base = (z * GG + y) * GG;
                int s = cs[base + x0], e = cs[base + x1 + 1];
#pragma unroll 1
                for (int i = s + lane; i < e; i += 64) {
                    float4 p = pts[i];
                    float dx = qx - p.x, dy2 = qy - p.y, dz2 = qz - p.z;
                    float t = dx * dx;
                    t = fmaf(dy2, dy2, t);
                    t = fmaf(dz2, dz2, t);
                    md = fminf(md, t);
                }
            }
        }
        float sv = md;
#pragma unroll
        for (int k = 2; k <= 64; k <<= 1) {
#pragma unroll
            for (int j2 = k >> 1; j2 >= 1; j2 >>= 1) {
                const bool want_min = (((lane & j2) == 0) == ((lane & k) == 0));
                float ov = __shfl_xor(sv, j2);
                sv = want_min ? fminf(sv, ov) : fmaxf(sv, ov);
            }
        }
        S16 = __shfl(sv, KNB - 1);
        if (S16 < FLT_BIG || R >= GG) break;
    }
    // --- grow R until min possible d2 outside cube(R) exceeds S16.
    // Exact box-distance from q's TRUE coords (handles clamped outliers: any
    // point in an unvisited cell lies at/beyond that cell's region).
#pragma unroll 1
    for (; R < GG; ++R) {
        float lox = LO_BOUND + (float)(cx - R) * H_CELL;
        float hix = LO_BOUND + (float)(cx + R + 1) * H_CELL;
        float loy = LO_BOUND + (float)(cy - R) * H_CELL;
        float hiy = LO_BOUND + (float)(cy + R + 1) * H_CELL;
        float loz = LO_BOUND + (float)(cz - R) * H_CELL;
        float hiz = LO_BOUND + (float)(cz + R + 1) * H_CELL;
        float m = fminf(fminf(qx - lox, hix - qx),
                  fminf(fminf(qy - loy, hiy - qy),
                        fminf(qz - loz, hiz - qz)));
        if (m > 0.f && m * m > S16) break;
    }
    // --- collect pass over cube(R): d2 <= S16 (>=16 guaranteed; ties kept)
    int cnt = 0;
#pragma unroll 1
    for (int dz = -R; dz <= R; ++dz) {
        int z = cz + dz;
        if (z < 0 || z >= GG) continue;
#pragma unroll 1
        for (int dy = -R; dy <= R; ++dy) {
            int y = cy + dy;
            if (y < 0 || y >= GG) continue;
            int x0 = max(0, cx - R), x1 = min(GG - 1, cx + R);
            int base = (z * GG + y) * GG;
            int s = cs[base + x0], e = cs[base + x1 + 1];
#pragma unroll 1
            for (int i0 = s; i0 < e; i0 += 64) {
                int i = i0 + lane;
                bool pred = false;
                float t = 0.f; int oid = 0;
                if (i < e) {
                    float4 p = pts[i];
                    float dx = qx - p.x, dy2 = qy - p.y, dz2 = qz - p.z;
                    t = dx * dx;
                    t = fmaf(dy2, dy2, t);
                    t = fmaf(dz2, dz2, t);
                    oid = __float_as_int(p.w);
                    pred = (t <= S16);
                }
                unsigned long long bal = __ballot(pred);
                if (bal) {
                    int pre = __builtin_amdgcn_mbcnt_hi((unsigned)(bal >> 32),
                              __builtin_amdgcn_mbcnt_lo((unsigned)bal, 0u));
                    int pos = cnt + pre;
                    if (pred && pos < CAPK) { bufd[w][pos] = t; bufi[w][pos] = oid; }
                    cnt += __popcll(bal);
                }
            }
        }
    }
    // --- final select: bitonic (cnt<=64) / rank loop (<=128) / brute fallback
    int* outq = cand_i + (size_t)q * KNB;
    if (cnt <= 64) {
        bool valid = (lane < cnt);
        float dv = valid ? bufd[w][lane] : FLT_BIG;
        int   iv = valid ? bufi[w][lane] : 0x7FFFFFFF;
#pragma unroll
        for (int k = 2; k <= 64; k <<= 1) {
#pragma unroll
            for (int j2 = k >> 1; j2 >= 1; j2 >>= 1) {
                const bool want_min = (((lane & j2) == 0) == ((lane & k) == 0));
                float od = __shfl_xor(dv, j2);
                int   oi = __shfl_xor(iv, j2);
                bool mine_less = (dv < od) || (dv == od && iv < oi);
                bool keep = (mine_less == want_min);
                dv = keep ? dv : od;
                iv = keep ? iv : oi;
            }
        }
        if (lane < KNB) outq[lane] = iv;
    } else if (cnt <= CAPK) {
#pragma unroll 1
        for (int half = 0; half < 2; ++half) {
            int i = lane + 64 * half;
            if (i < cnt) {
                float di = bufd[w][i]; int xi = bufi[w][i];
                int rank = 0;
                for (int t = 0; t < cnt; ++t) {
                    float dt = bufd[w][t]; int xt = bufi[w][t];
                    rank += (dt < di || (dt == di && xt < xi)) ? 1 : 0;
                }
                if (rank < KNB) outq[rank] = xi;
            }
        }
    } else {
        knn_fullN_r25(base4, qx, qy, qz, lane, outq);
    }
}

// pre-BN pos/feat matmul for one (k,h) pair — packed-fp32 over the reduction dim
__device__ __forceinline__ void prebn_r25(const float (*posf)[12], const float (*nf)[C_IN],
                                          int k,
                                          const f32x2* __restrict__ wp2, float bp,
                                          const f32x2* __restrict__ wf2, float bf,
                                          float* a_out, float* f_out) {
    const f32x2* pp = reinterpret_cast<const f32x2*>(&posf[k][0]);
    f32x2 a2 = pp[0] * wp2[0];
    a2 = pp[1] * wp2[1] + a2;
    a2 = pp[2] * wp2[2] + a2;
    a2 = pp[3] * wp2[3] + a2;
    a2 = pp[4] * wp2[4] + a2;
    const f32x2* nn2 = reinterpret_cast<const f32x2*>(&nf[k][0]);
    f32x2 f2 = nn2[0] * wf2[0];
#pragma unroll
    for (int t = 1; t < 16; ++t) f2 = nn2[t] * wf2[t] + f2;
    *a_out = bp + a2.x + a2.y;
    *f_out = bf + f2.x + f2.y;
}

// ---------------- stage A: gather + pre-BN + combpre store + partials (merge gone) ----------------
__global__ __launch_bounds__(256) void stageA_r25(const float* __restrict__ xyz4,
                                                  const int* __restrict__ sample_idx,
                                                  const float* __restrict__ featsT,
                                                  const int* __restrict__ cand_i,
                                                  const float* __restrict__ W_pos, const float* __restrict__ b_pos,
                                                  const float* __restrict__ W_feat, const float* __restrict__ b_feat,
                                                  const float* __restrict__ W_sc1, const float* __restrict__ W_sc2,
                                                  float* __restrict__ combpre,
                                                  float* __restrict__ sc1_pre, float* __restrict__ sc2_pre,
                                                  float* __restrict__ partialsA) {
    __shared__ __align__(16) float posf[4][KNB][12];
    __shared__ __align__(16) float nf[4][KNB][C_IN];
    __shared__ float meanf[4][C_IN];
    __shared__ float centerf[4][C_IN];
    __shared__ float posS[4][H_DIM], posQ[4][H_DIM], featS[4][H_DIM], featQ[4][H_DIM];
    __shared__ float s1S[4][D_DIM], s1Q[4][D_DIM], s2S[4][D_DIM], s2Q[4][D_DIM];
    const int tid = threadIdx.x;
    const int w = tid >> 6, lane = tid & 63;
    const int q = blockIdx.x * 4 + w;
    const int b = q >> 12;
    const int sidx = clampi_r25(sample_idx[q], 0, NN - 1);
    const float* base4 = xyz4 + (size_t)b * NN * 4;

    int imv = 0x7FFFFFFF;
    if (lane < KNB) imv = cand_i[(size_t)q * KNB + lane];
    float qx = base4[(size_t)sidx * 4 + 0];
    float qy = base4[(size_t)sidx * 4 + 1];
    float qz = base4[(size_t)sidx * 4 + 2];
    if (lane < C_IN) centerf[w][lane] = featsT[((size_t)b * NN + sidx) * C_IN + lane];

    if (lane < KNB) {
        int idx = clampi_r25(imv, 0, NN - 1);
        float nx = base4[(size_t)idx * 4 + 0];
        float ny = base4[(size_t)idx * 4 + 1];
        float nz = base4[(size_t)idx * 4 + 2];
        float rx = qx - nx, ry = qy - ny, rz = qz - nz;
        float dist = sqrtf(rx * rx + ry * ry + rz * rz);
        posf[w][lane][0] = qx; posf[w][lane][1] = qy; posf[w][lane][2] = qz;
        posf[w][lane][3] = nx; posf[w][lane][4] = ny; posf[w][lane][5] = nz;
        posf[w][lane][6] = rx; posf[w][lane][7] = ry; posf[w][lane][8] = rz;
        posf[w][lane][9] = dist; posf[w][lane][10] = 0.f; posf[w][lane][11] = 0.f;
    }
    const float* fT = featsT + (size_t)b * NN * C_IN;
#pragma unroll
    for (int ii = 0; ii < 2; ++ii) {
        int e4 = lane + 64 * ii;
        int k = e4 >> 3, c4 = e4 & 7;
        int idx = clampi_r25(__shfl(imv, k), 0, NN - 1);
        const float4 v = *reinterpret_cast<const float4*>(fT + (size_t)idx * C_IN + c4 * 4);
        *reinterpret_cast<float4*>(&nf[w][k][c4 * 4]) = v;
    }

    const int h = lane & 31;
    f32x2 wp2[5], wf2[16];
#pragma unroll
    for (int t = 0; t < 5; ++t)
        wp2[t] = mk2_r25(W_pos[(2 * t) * H_DIM + h], W_pos[(2 * t + 1) * H_DIM + h]);
#pragma unroll
    for (int t = 0; t < 16; ++t)
        wf2[t] = mk2_r25(W_feat[(2 * t) * H_DIM + h], W_feat[(2 * t + 1) * H_DIM + h]);
    const float bp = b_pos[h], bf = b_feat[h];

    float sP = 0.f, qP = 0.f, sF = 0.f, qF = 0.f;
    float* cp = combpre + (size_t)q * (KNB * D_DIM);
#pragma unroll
    for (int i2 = 0; i2 < 8; i2++) {
        int k = ((lane + 64 * i2) >> 5);
        float a, f;
        prebn_r25(posf[w], nf[w], k, wp2, bp, wf2, bf, &a, &f);
        sP += a; qP += a * a;
        sF += f; qF += f * f;
        cp[k * D_DIM + h] = f;
        cp[k * D_DIM + H_DIM + h] = a;
    }
    sP += __shfl_xor(sP, 32); qP += __shfl_xor(qP, 32);
    sF += __shfl_xor(sF, 32); qF += __shfl_xor(qF, 32);
    if (lane < H_DIM) {
        posS[w][h] = sP; posQ[w][h] = qP; featS[w][h] = sF; featQ[w][h] = qF;
    }
    if (lane < C_IN) {
        float s = 0.f;
#pragma unroll
        for (int k = 0; k < KNB; k++) s += nf[w][k][lane];
        meanf[w][lane] = s * (1.f / (float)KNB);
    }
    {
        float a = 0.f, c2 = 0.f;
#pragma unroll
        for (int j = 0; j < C_IN; j++) {
            a  += meanf[w][j]   * W_sc1[j * D_DIM + lane];
            c2 += centerf[w][j] * W_sc2[j * D_DIM + lane];
        }
        sc1_pre[(size_t)q * D_DIM + lane] = a;
        sc2_pre[(size_t)q * D_DIM + lane] = c2;
        s1S[w][lane] = a;  s1Q[w][lane] = a * a;
        s2S[w][lane] = c2; s2Q[w][lane] = c2 * c2;
    }
    __syncthreads();
    float* row = partialsA + (size_t)blockIdx.x * PA_W;
    if (tid < H_DIM) {
        row[SPOS_SUM + tid]  = posS[0][tid] + posS[1][tid] + posS[2][tid] + posS[3][tid];
        row[SPOS_SQ + tid]   = posQ[0][tid] + posQ[1][tid] + posQ[2][tid] + posQ[3][tid];
        row[SFEAT_SUM + tid] = featS[0][tid] + featS[1][tid] + featS[2][tid] + featS[3][tid];
        row[SFEAT_SQ + tid]  = featQ[0][tid] + featQ[1][tid] + featQ[2][tid] + featQ[3][tid];
    } else if (tid >= 64 && tid < 128) {
        int dd = tid - 64;
        row[SSC1_SUM + dd] = s1S[0][dd] + s1S[1][dd] + s1S[2][dd] + s1S[3][dd];
        row[SSC1_SQ + dd]  = s1Q[0][dd] + s1Q[1][dd] + s1Q[2][dd] + s1Q[3][dd];
    } else if (tid >= 128 && tid < 192) {
        int dd = tid - 128;
        row[SSC2_SUM + dd] = s2S[0][dd] + s2S[1][dd] + s2S[2][dd] + s2S[3][dd];
        row[SSC2_SQ + dd]  = s2Q[0][dd] + s2Q[1][dd] + s2Q[2][dd] + s2Q[3][dd];
    }
}

// ---------------- generic split reduce ----------------
#define NRSPLIT 64
__global__ __launch_bounds__(256) void reduce_r25(const float* __restrict__ partials,
                                                  int rows, int width,
                                                  float* __restrict__ stats_out) {
    const int wchunks = (width + 255) / 256;
    const int wi = blockIdx.x % wchunks;
    const int pi = blockIdx.x / wchunks;
    const int c = wi * 256 + threadIdx.x;
    if (c >= width) return;
    const int per = rows / NRSPLIT;
    const int p0 = pi * per;
    float s = 0.f;
    for (int p = p0; p < p0 + per; ++p) s += partials[(size_t)p * width + c];
    atomicAdd(&stats_out[c], s);
}

// ---------------- stage B: stream combpre -> BN -> softmax -> pooled -> W_out ----------------
__global__ __launch_bounds__(256) void stageB_r25(const float* __restrict__ combpre,
                                                  const float* __restrict__ g_pos, const float* __restrict__ be_pos,
                                                  const float* __restrict__ g_feat, const float* __restrict__ be_feat,
                                                  const float* __restrict__ W_score, const float* __restrict__ W_out,
                                                  const float* __restrict__ stats,
                                                  float* __restrict__ out_pre,
                                                  float* __restrict__ partialsB) {
    __shared__ __align__(16) float comb[4][KNB][D_DIM];
    __shared__ float scl[D_DIM], shf[D_DIM];
    __shared__ float pooled[4][D_DIM];
    __shared__ float oS[4][D_DIM], oQ[4][D_DIM];
    const int tid = threadIdx.x;
    const int w = tid >> 6, lane = tid & 63;
    const int q = blockIdx.x * 4 + w;

    if (tid < D_DIM) {
        const float inv1 = 1.f / (float)(BB * MM * KNB);
        float mean, var, g, bb;
        if (tid < H_DIM) {
            mean = stats[SFEAT_SUM + tid] * inv1;
            var  = fmaxf(stats[SFEAT_SQ + tid] * inv1 - mean * mean, 0.f);
            g = g_feat[tid]; bb = be_feat[tid];
        } else {
            int h = tid - H_DIM;
            mean = stats[SPOS_SUM + h] * inv1;
            var  = fmaxf(stats[SPOS_SQ + h] * inv1 - mean * mean, 0.f);
            g = g_pos[h]; bb = be_pos[h];
        }
        float s = g * rsqrtf(var + EPSV);
        scl[tid] = s;
        shf[tid] = bb - mean * s;
    }
    __syncthreads();

    const float4* src = reinterpret_cast<const float4*>(combpre + (size_t)blockIdx.x * 4 * KNB * D_DIM);
#pragma unroll
    for (int i = 0; i < 4; ++i) {
        int f = tid + 256 * i;
        int qloc = f >> 8;
        int k = (f >> 4) & 15;
        int j4 = f & 15;
        float4 v = src[f];
        int j = j4 * 4;
        v.x = fmaxf(v.x * scl[j + 0] + shf[j + 0], 0.f);
        v.y = fmaxf(v.y * scl[j + 1] + shf[j + 1], 0.f);
        v.z = fmaxf(v.z * scl[j + 2] + shf[j + 2], 0.f);
        v.w = fmaxf(v.w * scl[j + 3] + shf[j + 3], 0.f);
        *reinterpret_cast<float4*>(&comb[qloc][k][j]) = v;
    }
    __syncthreads();

    const int d = lane;
    f32x2 s2[KNB];
#pragma unroll
    for (int k = 0; k < KNB; k++) s2[k] = mk2_r25(0.f, 0.f);
#pragma unroll 4
    for (int j4 = 0; j4 < D_DIM / 4; ++j4) {
        f32x2 wA = mk2_r25(W_score[(j4 * 4 + 0) * D_DIM + d],
                           W_score[(j4 * 4 + 1) * D_DIM + d]);
        f32x2 wB = mk2_r25(W_score[(j4 * 4 + 2) * D_DIM + d],
                           W_score[(j4 * 4 + 3) * D_DIM + d]);
#pragma unroll
        for (int k = 0; k < KNB; k++) {
            const f32x2* cb = reinterpret_cast<const f32x2*>(&comb[w][k][j4 * 4]);
            s2[k] = cb[0] * wA + s2[k];
            s2[k] = cb[1] * wB + s2[k];
        }
    }
    float s[KNB];
#pragma unroll
    for (int k = 0; k < KNB; k++) s[k] = s2[k].x + s2[k].y;
    float mx = s[0];
#pragma unroll
    for (int k = 1; k < KNB; k++) mx = fmaxf(mx, s[k]);
    float sum = 0.f;
#pragma unroll
    for (int k = 0; k < KNB; k++) { s[k] = __expf(s[k] - mx); sum += s[k]; }
    float inv = 1.f / sum;
    float pv = 0.f;
#pragma unroll
    for (int k = 0; k < KNB; k++) pv += s[k] * inv * comb[w][k][d];
    pooled[w][d] = pv;
    __syncthreads();
    float o = 0.f;
#pragma unroll
    for (int dd = 0; dd < D_DIM; dd++) o += pooled[w][dd] * W_out[dd * D_DIM + d];
    out_pre[(size_t)q * D_DIM + d] = o;
    oS[w][d] = o; oQ[w][d] = o * o;
    __syncthreads();
    float* row = partialsB + (size_t)blockIdx.x * PB_W;
    if (tid < D_DIM) {
        row[tid] = oS[0][tid] + oS[1][tid] + oS[2][tid] + oS[3][tid];
    } else if (tid < 2 * D_DIM) {
        int dd = tid - D_DIM;
        row[D_DIM + dd] = oQ[0][dd] + oQ[1][dd] + oQ[2][dd] + oQ[3][dd];
    }
}

// ---------------- final ----------------
__global__ __launch_bounds__(256) void final_r25(const float* __restrict__ out_pre,
                                                 const float* __restrict__ sc1_pre,
                                                 const float* __restrict__ sc2_pre,
                                                 const float* __restrict__ stats,
                                                 const float* __restrict__ g_out, const float* __restrict__ be_out,
                                                 const float* __restrict__ g_sc1, const float* __restrict__ be_sc1,
                                                 const float* __restrict__ g_sc2, const float* __restrict__ be_sc2,
                                                 float* __restrict__ out) {
    __shared__ float yt[64][65];
    const int tid = threadIdx.x;
    const int blk = blockIdx.x;
    const int b = blk >> 6;
    const int m0 = (blk & 63) * 64;
    const int d = tid & 63;

    const float invn = 1.f / (float)(BB * MM);
    float mo = stats[SOUT_SUM + d] * invn;
    float vo = fmaxf(stats[SOUT_SQ + d] * invn - mo * mo, 0.f);
    float so = g_out[d] * rsqrtf(vo + EPSV);
    float oo = be_out[d] - mo * so;
    float m1 = stats[SSC1_SUM + d] * invn;
    float v1 = fmaxf(stats[SSC1_SQ + d] * invn - m1 * m1, 0.f);
    float s1 = g_sc1[d] * rsqrtf(v1 + EPSV);
    float o1 = be_sc1[d] - m1 * s1;
    float m2 = stats[SSC2_SUM + d] * invn;
    float v2 = fmaxf(stats[SSC2_SQ + d] * invn - m2 * m2, 0.f);
    float s2 = g_sc2[d] * rsqrtf(v2 + EPSV);
    float o2 = be_sc2[d] - m2 * s2;

#pragma unroll
    for (int p = 0; p < 16; p++) {
        int ml = (tid >> 6) + 4 * p;
        size_t q = (size_t)b * MM + m0 + ml;
        float x_out = fmaxf(out_pre[q * D_DIM + d] * so + oo, 0.f);
        float x1 = sc1_pre[q * D_DIM + d] * s1 + o1;
        float x2 = sc2_pre[q * D_DIM + d] * s2 + o2;
        yt[ml][d] = fmaxf(x_out + x1 + x2, 0.f);
    }
    __syncthreads();
#pragma unroll
    for (int p = 0; p < 16; p++) {
        int dr = (tid >> 6) + 4 * p;
        int mc = tid & 63;
        out[BB * MM * 3 + (size_t)b * (D_DIM * MM) + (size_t)dr * MM + m0 + mc] = yt[mc][dr];
    }
}

extern "C" void kernel_launch(void* const* d_in, const int* in_sizes, int n_in,
                              void* d_out, int out_size, void* d_ws, size_t ws_size,
                              hipStream_t stream) {
    const float* xyz        = (const float*)d_in[0];
    const float* feats      = (const float*)d_in[1];
    const int*   sample_idx = (const int*)d_in[2];
    const float* W_pos  = (const float*)d_in[3];
    const float* b_pos  = (const float*)d_in[4];
    const float* g_pos  = (const float*)d_in[5];
    const float* be_pos = (const float*)d_in[6];
    const float* W_feat  = (const float*)d_in[7];
    const float* b_feat  = (const float*)d_in[8];
    const float* g_feat  = (const float*)d_in[9];
    const float* be_feat = (const float*)d_in[10];
    const float* W_score = (const float*)d_in[11];
    const float* W_out  = (const float*)d_in[12];
    const float* g_out  = (const float*)d_in[13];
    const float* be_out = (const float*)d_in[14];
    const float* W_sc1  = (const float*)d_in[15];
    const float* g_sc1  = (const float*)d_in[16];
    const float* be_sc1 = (const float*)d_in[17];
    const float* W_sc2  = (const float*)d_in[18];
    const float* g_sc2  = (const float*)d_in[19];
    const float* be_sc2 = (const float*)d_in[20];

    float* out = (float*)d_out;
    float* ws = (float*)d_ws;

    float* featsT    = ws;                                   // 1,048,576
    float* xyz4      = featsT + 1048576;                     //   131,072
    float* sc1_pre   = xyz4 + 131072;                        //   524,288
    float* sc2_pre   = sc1_pre + 524288;                     //   524,288
    float* out_pre   = sc2_pre + 524288;                     //   524,288
    float* stats     = out_pre + 524288;                     //       512
    float* partialsA = stats + STATS_LEN;                    //   786,432
    float* partialsB = partialsA + NBLK * PA_W;              //   262,144
    int*   cand_i    = (int*)(partialsB + NBLK * PB_W);      //   131,072 ints
    int*   cellcnt   = cand_i + BB * MM * KNB;               //    65,536 ints
    int*   cellstart = cellcnt + BB * G3;                    //    65,538 ints
    int*   cursor    = cellstart + BB * (G3 + 1);            //    65,536 ints
    float* xyzr      = (float*)(cursor + BB * G3);           //   131,072 floats
    float* combpre   = xyzr + BB * NN * 4;                   // 8,388,608 (32 MB)

    prep_r25<<<BB * (NN / 64), 256, 0, stream>>>(feats, xyz, sample_idx,
                                                 featsT, xyz4, stats, cellcnt, out);

    hist_r25<<<BB * NN / 256, 256, 0, stream>>>(xyz, cellcnt);

    scan_r25<<<BB, 256, 0, stream>>>(cellcnt, cellstart, cursor);

    scatter_r25<<<BB * NN / 256, 256, 0, stream>>>(xyz, cursor, xyzr);

    knnq_r25<<<BB * MM / 4, 256, 0, stream>>>(xyz4, sample_idx, cellstart, xyzr, cand_i);

    stageA_r25<<<NBLK, 256, 0, stream>>>(xyz4, sample_idx, featsT, cand_i,
                                         W_pos, b_pos, W_feat, b_feat, W_sc1, W_sc2,
                                         combpre, sc1_pre, sc2_pre, partialsA);
    reduce_r25<<<2 * NRSPLIT, 256, 0, stream>>>(partialsA, NBLK, PA_W, stats);

    stageB_r25<<<NBLK, 256, 0, stream>>>(combpre,
                                         g_pos, be_pos, g_feat, be_feat,
                                         W_score, W_out, stats, out_pre, partialsB);
    reduce_r25<<<1 * NRSPLIT, 256, 0, stream>>>(partialsB, NBLK, PB_W, stats + SOUT_SUM);

    final_r25<<<BB * (MM / 64), 256, 0, stream>>>(out_pre, sc1_pre, sc2_pre, stats,
                                                  g_out, be_out, g_sc1, be_sc1, g_sc2, be_sc2, out);
}

// Round 10
// 348.823 us; speedup vs baseline: 2.0340x; 2.0340x over previous
//
#include <hip/hip_runtime.h>
#include <math.h>

#define BB 2
#define NN 16384
#define MM 4096
#define C_IN 32
#define D_DIM 64
#define H_DIM 32
#define KNB 16
#define EPSV 1e-5f
#define FLT_BIG 3.0e38f
#define CAPK 128
#define GG 8
#define G3 (GG * GG * GG)
#define LO_BOUND (-5.0f)
#define H_CELL (10.0f / (float)GG)
#define INV_H ((float)GG / 10.0f)

// stats layout (floats)
#define SPOS_SUM 0
#define SPOS_SQ 32
#define SFEAT_SUM 64
#define SFEAT_SQ 96
#define SSC1_SUM 128
#define SSC1_SQ 192
#define SSC2_SUM 256
#define SSC2_SQ 320
#define SOUT_SUM 384
#define SOUT_SQ 448
#define STATS_LEN 512
#define PA_W 384
#define PB_W 128
#define NBLK (BB * MM / 4)

typedef float f32x2 __attribute__((ext_vector_type(2)));

__device__ __forceinline__ f32x2 mk2_r26(float a, float b) {
    f32x2 r; r.x = a; r.y = b; return r;
}

__device__ __forceinline__ int clampi_r26(int v, int lo, int hi) {
    return v < lo ? lo : (v > hi ? hi : v);
}

__device__ __forceinline__ int cell_of_r26(float v) {
    int c = (int)floorf((v - LO_BOUND) * INV_H);
    return clampi_r26(c, 0, GG - 1);
}

// ---------------- prep: transpose + xyz4 + outputs 0&2 + stats/cellcnt zero ----------------
__global__ __launch_bounds__(256) void prep_r26(const float* __restrict__ feats,
                                                const float* __restrict__ xyz,
                                                const int* __restrict__ sample_idx,
                                                float* __restrict__ featsT,
                                                float* __restrict__ xyz4,
                                                float* __restrict__ stats,
                                                int* __restrict__ cellcnt,
                                                float* __restrict__ out) {
    __shared__ float tile[C_IN][65];
    const int tid = threadIdx.x;
    const int b = blockIdx.x >> 8;
    const int n0 = (blockIdx.x & 255) * 64;
#pragma unroll
    for (int it = 0; it < 8; ++it) {
        int c = (tid >> 6) + 4 * it;
        int n = tid & 63;
        tile[c][n] = feats[((size_t)b * C_IN + c) * NN + n0 + n];
    }
    int e = blockIdx.x * 256 + tid;
    if (e < STATS_LEN) stats[e] = 0.f;
    if (e < BB * G3) cellcnt[e] = 0;
    if (e < BB * NN) {
        float x = xyz[e * 3 + 0], y = xyz[e * 3 + 1], z = xyz[e * 3 + 2];
        xyz4[e * 4 + 0] = x;
        xyz4[e * 4 + 1] = y;
        xyz4[e * 4 + 2] = z;
        xyz4[e * 4 + 3] = x * x + y * y + z * z;
    }
    if (e < BB * MM) {
        int bb2 = e >> 12;
        int sidx = clampi_r26(sample_idx[e], 0, NN - 1);
        const float* p = xyz + (size_t)(bb2 * NN + sidx) * 3;
        out[e * 3 + 0] = p[0];
        out[e * 3 + 1] = p[1];
        out[e * 3 + 2] = p[2];
        out[BB * MM * 3 + BB * D_DIM * MM + e] = (float)sample_idx[e];
    }
    __syncthreads();
#pragma unroll
    for (int it = 0; it < 8; ++it) {
        int c = tid & 31;
        int nn = (tid >> 5) + 8 * it;
        featsT[((size_t)b * NN + n0 + nn) * C_IN + c] = tile[c][nn];
    }
}

// ---------------- hist: count points per cell ----------------
__global__ __launch_bounds__(256) void hist_r26(const float* __restrict__ xyz,
                                                int* __restrict__ cellcnt) {
    int e = blockIdx.x * 256 + threadIdx.x;
    if (e >= BB * NN) return;
    int b = e >> 14;
    float x = xyz[e * 3 + 0], y = xyz[e * 3 + 1], z = xyz[e * 3 + 2];
    int cid = (cell_of_r26(z) * GG + cell_of_r26(y)) * GG + cell_of_r26(x);
    atomicAdd(&cellcnt[b * G3 + cid], 1);
}

// ---------------- scan: per-batch exclusive prefix over G3 cells ----------------
__global__ __launch_bounds__(256) void scan_r26(const int* __restrict__ cellcnt,
                                                int* __restrict__ cellstart,
                                                int* __restrict__ cursor) {
    __shared__ int psum[256];
    const int b = blockIdx.x;
    const int tid = threadIdx.x;
    const int cbase = b * G3;
    const int sbase = b * (G3 + 1);
    const int CH = G3 / 256;   // cells per thread
    int s = 0;
#pragma unroll 1
    for (int i = tid * CH; i < (tid + 1) * CH; ++i) s += cellcnt[cbase + i];
    psum[tid] = s;
    __syncthreads();
    for (int off = 1; off < 256; off <<= 1) {
        int t = (tid >= off) ? psum[tid - off] : 0;
        __syncthreads();
        psum[tid] += t;
        __syncthreads();
    }
    int run = (tid == 0) ? 0 : psum[tid - 1];
#pragma unroll 1
    for (int i = tid * CH; i < (tid + 1) * CH; ++i) {
        cellstart[sbase + i] = run;
        cursor[cbase + i] = run;
        run += cellcnt[cbase + i];
    }
    if (tid == 255) cellstart[sbase + G3] = run;
}

// ---------------- scatter: reorder points cell-contiguous, idx in .w ----------------
__global__ __launch_bounds__(256) void scatter_r26(const float* __restrict__ xyz,
                                                   int* __restrict__ cursor,
                                                   float* __restrict__ xyzr) {
    int e = blockIdx.x * 256 + threadIdx.x;
    if (e >= BB * NN) return;
    int b = e >> 14;
    int n = e & (NN - 1);
    float x = xyz[e * 3 + 0], y = xyz[e * 3 + 1], z = xyz[e * 3 + 2];
    int cid = (cell_of_r26(z) * GG + cell_of_r26(y)) * GG + cell_of_r26(x);
    int pos = atomicAdd(&cursor[b * G3 + cid], 1);
    float4* dst = reinterpret_cast<float4*>(xyzr) + (size_t)b * NN + pos;
    float4 v;
    v.x = x; v.y = y; v.z = z; v.w = __int_as_float(n);
    *dst = v;
}

// whole-batch exact scan fallback (only if candidate buffer overflows — ~never)
__device__ void knn_fullN_r26(const float* __restrict__ base4,
                              float qx, float qy, float qz, int lane,
                              int* __restrict__ outi) {
    float d2v[KNB]; int iv[KNB];
#pragma unroll
    for (int i = 0; i < KNB; i++) { d2v[i] = FLT_BIG; iv[i] = 0x7FFFFFFF; }
    float curmax = FLT_BIG; int amax = 0;
    for (int n = lane; n < NN; n += 64) {
        const float4 p = *reinterpret_cast<const float4*>(base4 + (size_t)n * 4);
        float dx = qx - p.x, dy = qy - p.y, dz = qz - p.z;
        float d2 = dx * dx;
        d2 = fmaf(dy, dy, d2);
        d2 = fmaf(dz, dz, d2);
        if (d2 < curmax) {
#pragma unroll
            for (int i = 0; i < KNB; i++)
                if (i == amax) { d2v[i] = d2; iv[i] = n; }
            curmax = d2v[0]; amax = 0;
#pragma unroll
            for (int i = 1; i < KNB; i++)
                if (d2v[i] > curmax) { curmax = d2v[i]; amax = i; }
        }
    }
#pragma unroll
    for (int i = 0; i < KNB; i++) {
#pragma unroll
        for (int j = 0; j < KNB - 1; j++) {
            bool sw = (d2v[j] > d2v[j + 1]) ||
                      (d2v[j] == d2v[j + 1] && iv[j] > iv[j + 1]);
            if (sw) {
                float td = d2v[j]; d2v[j] = d2v[j + 1]; d2v[j + 1] = td;
                int   ti = iv[j];  iv[j]  = iv[j + 1];  iv[j + 1]  = ti;
            }
        }
    }
#pragma unroll 1
    for (int r = 0; r < KNB; r++) {
        float cv = d2v[0]; int cid = iv[0]; int ml = lane;
#pragma unroll
        for (int off = 32; off > 0; off >>= 1) {
            float ov = __shfl_xor(cv, off);
            int   oid = __shfl_xor(cid, off);
            int   ol = __shfl_xor(ml, off);
            bool take = (ov < cv) || (ov == cv && oid < cid);
            cv = take ? ov : cv; cid = take ? oid : cid; ml = take ? ol : ml;
        }
        if (lane == r) outi[r] = cid;
        if (lane == ml) {
#pragma unroll
            for (int i = 0; i < KNB - 1; i++) { d2v[i] = d2v[i + 1]; iv[i] = iv[i + 1]; }
            d2v[KNB - 1] = FLT_BIG; iv[KNB - 1] = 0x7FFFFFFF;
        }
    }
}

// ---------------- knnq: exact grid-binned KNN, one wave per query (G=8 coarse) ----------------
__global__ __launch_bounds__(256) void knnq_r26(const float* __restrict__ xyz4,
                                                const int* __restrict__ sample_idx,
                                                const int* __restrict__ cellstart,
                                                const float* __restrict__ xyzr,
                                                int* __restrict__ cand_i) {
    __shared__ float bufd[4][CAPK];
    __shared__ int   bufi[4][CAPK];
    const int tid = threadIdx.x;
    const int w = tid >> 6, lane = tid & 63;
    const int q = blockIdx.x * 4 + w;
    const int b = q >> 12;
    const int sidx = clampi_r26(sample_idx[q], 0, NN - 1);
    const float* base4 = xyz4 + (size_t)b * NN * 4;
    const float qx = base4[(size_t)sidx * 4 + 0];
    const float qy = base4[(size_t)sidx * 4 + 1];
    const float qz = base4[(size_t)sidx * 4 + 2];
    const int cx = cell_of_r26(qx), cy = cell_of_r26(qy), cz = cell_of_r26(qz);
    const int* cs = cellstart + (size_t)b * (G3 + 1);
    const float4* pts = reinterpret_cast<const float4*>(xyzr) + (size_t)b * NN;

    // --- seed radius: start at R=1 (27 cells, ~864 pts at G=8); grow only if <16
    int R = 1;
#pragma unroll 1
    for (;; ++R) {
        int c = 0;
#pragma unroll 1
        for (int dz = -R; dz <= R; ++dz) {
            int z = cz + dz;
            if (z < 0 || z >= GG) continue;
#pragma unroll 1
            for (int dy = -R; dy <= R; ++dy) {
                int y = cy + dy;
                if (y < 0 || y >= GG) continue;
                int x0 = max(0, cx - R), x1 = min(GG - 1, cx + R);
                int base = (z * GG + y) * GG;
                c += cs[base + x1 + 1] - cs[base + x0];
            }
        }
        if (c >= KNB || R >= GG) break;
    }
    // --- seed bound S16: 16th-smallest of 64 lane-mins over cube(R).
    // >=16 distinct points (16 lanes' min points, disjoint lane sets) have
    // d2 <= S16 => valid upper bound on the true 16th-NN distance.
    float S16;
#pragma unroll 1
    for (;; ++R) {
        float md = FLT_BIG;
#pragma unroll 1
        for (int dz = -R; dz <= R; ++dz) {
            int z = cz + dz;
            if (z < 0 || z >= GG) continue;
#pragma unroll 1
            for (int dy = -R; dy <= R; ++dy) {
                int y = cy + dy;
                if (y < 0 || y >= GG) continue;
                int x0 = max(0, cx - R), x1 = min(GG - 1, cx + R);
                int base = (z * GG + y) * GG;
                int s = cs[base + x0], e = cs[base + x1 + 1];
#pragma unroll 1
                for (int i = s + lane; i < e; i += 64) {
                    float4 p = pts[i];
                    float dx = qx - p.x, dy2 = qy - p.y, dz2 = qz - p.z;
                    float t = dx * dx;
                    t = fmaf(dy2, dy2, t);
                    t = fmaf(dz2, dz2, t);
                    md = fminf(md, t);
                }
            }
        }
        float sv = md;
#pragma unroll
        for (int k = 2; k <= 64; k <<= 1) {
#pragma unroll
            for (int j2 = k >> 1; j2 >= 1; j2 >>= 1) {
                const bool want_min = (((lane & j2) == 0) == ((lane & k) == 0));
                float ov = __shfl_xor(sv, j2);
                sv = want_min ? fminf(sv, ov) : fmaxf(sv, ov);
            }
        }
        S16 = __shfl(sv, KNB - 1);
        if (S16 < FLT_BIG || R >= GG) break;
    }
    // --- grow R until min possible d2 outside cube(R) exceeds S16.
    // Exact box-distance from q's TRUE coords; unvisited points lie outside the
    // box, so dist >= margin m. (Out-of-grid box faces have no points — bound
    // stays conservative.)
#pragma unroll 1
    for (; R < GG; ++R) {
        float lox = LO_BOUND + (float)(cx - R) * H_CELL;
        float hix = LO_BOUND + (float)(cx + R + 1) * H_CELL;
        float loy = LO_BOUND + (float)(cy - R) * H_CELL;
        float hiy = LO_BOUND + (float)(cy + R + 1) * H_CELL;
        float loz = LO_BOUND + (float)(cz - R) * H_CELL;
        float hiz = LO_BOUND + (float)(cz + R + 1) * H_CELL;
        float m = fminf(fminf(qx - lox, hix - qx),
                  fminf(fminf(qy - loy, hiy - qy),
                        fminf(qz - loz, hiz - qz)));
        if (m > 0.f && m * m > S16) break;
    }
    // --- collect pass over cube(R): d2 <= S16 (>=16 guaranteed; ties kept)
    int cnt = 0;
#pragma unroll 1
    for (int dz = -R; dz <= R; ++dz) {
        int z = cz + dz;
        if (z < 0 || z >= GG) continue;
#pragma unroll 1
        for (int dy = -R; dy <= R; ++dy) {
            int y = cy + dy;
            if (y < 0 || y >= GG) continue;
            int x0 = max(0, cx - R), x1 = min(GG - 1, cx + R);
            int base = (z * GG + y) * GG;
            int s = cs[base + x0], e = cs[base + x1 + 1];
#pragma unroll 1
            for (int i0 = s; i0 < e; i0 += 64) {
                int i = i0 + lane;
                bool pred = false;
                float t = 0.f; int oid = 0;
                if (i < e) {
                    float4 p = pts[i];
                    float dx = qx - p.x, dy2 = qy - p.y, dz2 = qz - p.z;
                    t = dx * dx;
                    t = fmaf(dy2, dy2, t);
                    t = fmaf(dz2, dz2, t);
                    oid = __float_as_int(p.w);
                    pred = (t <= S16);
                }
                unsigned long long bal = __ballot(pred);
                if (bal) {
                    int pre = __builtin_amdgcn_mbcnt_hi((unsigned)(bal >> 32),
                              __builtin_amdgcn_mbcnt_lo((unsigned)bal, 0u));
                    int pos = cnt + pre;
                    if (pred && pos < CAPK) { bufd[w][pos] = t; bufi[w][pos] = oid; }
                    cnt += __popcll(bal);
                }
            }
        }
    }
    // --- final select: bitonic (cnt<=64) / rank loop (<=128) / brute fallback
    int* outq = cand_i + (size_t)q * KNB;
    if (cnt <= 64) {
        bool valid = (lane < cnt);
        float dv = valid ? bufd[w][lane] : FLT_BIG;
        int   iv = valid ? bufi[w][lane] : 0x7FFFFFFF;
#pragma unroll
        for (int k = 2; k <= 64; k <<= 1) {
#pragma unroll
            for (int j2 = k >> 1; j2 >= 1; j2 >>= 1) {
                const bool want_min = (((lane & j2) == 0) == ((lane & k) == 0));
                float od = __shfl_xor(dv, j2);
                int   oi = __shfl_xor(iv, j2);
                bool mine_less = (dv < od) || (dv == od && iv < oi);
                bool keep = (mine_less == want_min);
                dv = keep ? dv : od;
                iv = keep ? iv : oi;
            }
        }
        if (lane < KNB) outq[lane] = iv;
    } else if (cnt <= CAPK) {
#pragma unroll 1
        for (int half = 0; half < 2; ++half) {
            int i = lane + 64 * half;
            if (i < cnt) {
                float di = bufd[w][i]; int xi = bufi[w][i];
                int rank = 0;
                for (int t = 0; t < cnt; ++t) {
                    float dt = bufd[w][t]; int xt = bufi[w][t];
                    rank += (dt < di || (dt == di && xt < xi)) ? 1 : 0;
                }
                if (rank < KNB) outq[rank] = xi;
            }
        }
    } else {
        knn_fullN_r26(base4, qx, qy, qz, lane, outq);
    }
}

// pre-BN pos/feat matmul for one (k,h) pair — packed-fp32 over the reduction dim
__device__ __forceinline__ void prebn_r26(const float (*posf)[12], const float (*nf)[C_IN],
                                          int k,
                                          const f32x2* __restrict__ wp2, float bp,
                                          const f32x2* __restrict__ wf2, float bf,
                                          float* a_out, float* f_out) {
    const f32x2* pp = reinterpret_cast<const f32x2*>(&posf[k][0]);
    f32x2 a2 = pp[0] * wp2[0];
    a2 = pp[1] * wp2[1] + a2;
    a2 = pp[2] * wp2[2] + a2;
    a2 = pp[3] * wp2[3] + a2;
    a2 = pp[4] * wp2[4] + a2;
    const f32x2* nn2 = reinterpret_cast<const f32x2*>(&nf[k][0]);
    f32x2 f2 = nn2[0] * wf2[0];
#pragma unroll
    for (int t = 1; t < 16; ++t) f2 = nn2[t] * wf2[t] + f2;
    *a_out = bp + a2.x + a2.y;
    *f_out = bf + f2.x + f2.y;
}

// ---------------- stage A: gather + pre-BN + combpre store + partials ----------------
__global__ __launch_bounds__(256) void stageA_r26(const float* __restrict__ xyz4,
                                                  const int* __restrict__ sample_idx,
                                                  const float* __restrict__ featsT,
                                                  const int* __restrict__ cand_i,
                                                  const float* __restrict__ W_pos, const float* __restrict__ b_pos,
                                                  const float* __restrict__ W_feat, const float* __restrict__ b_feat,
                                                  const float* __restrict__ W_sc1, const float* __restrict__ W_sc2,
                                                  float* __restrict__ combpre,
                                                  float* __restrict__ sc1_pre, float* __restrict__ sc2_pre,
                                                  float* __restrict__ partialsA) {
    __shared__ __align__(16) float posf[4][KNB][12];
    __shared__ __align__(16) float nf[4][KNB][C_IN];
    __shared__ float meanf[4][C_IN];
    __shared__ float centerf[4][C_IN];
    __shared__ float posS[4][H_DIM], posQ[4][H_DIM], featS[4][H_DIM], featQ[4][H_DIM];
    __shared__ float s1S[4][D_DIM], s1Q[4][D_DIM], s2S[4][D_DIM], s2Q[4][D_DIM];
    const int tid = threadIdx.x;
    const int w = tid >> 6, lane = tid & 63;
    const int q = blockIdx.x * 4 + w;
    const int b = q >> 12;
    const int sidx = clampi_r26(sample_idx[q], 0, NN - 1);
    const float* base4 = xyz4 + (size_t)b * NN * 4;

    int imv = 0x7FFFFFFF;
    if (lane < KNB) imv = cand_i[(size_t)q * KNB + lane];
    float qx = base4[(size_t)sidx * 4 + 0];
    float qy = base4[(size_t)sidx * 4 + 1];
    float qz = base4[(size_t)sidx * 4 + 2];
    if (lane < C_IN) centerf[w][lane] = featsT[((size_t)b * NN + sidx) * C_IN + lane];

    if (lane < KNB) {
        int idx = clampi_r26(imv, 0, NN - 1);
        float nx = base4[(size_t)idx * 4 + 0];
        float ny = base4[(size_t)idx * 4 + 1];
        float nz = base4[(size_t)idx * 4 + 2];
        float rx = qx - nx, ry = qy - ny, rz = qz - nz;
        float dist = sqrtf(rx * rx + ry * ry + rz * rz);
        posf[w][lane][0] = qx; posf[w][lane][1] = qy; posf[w][lane][2] = qz;
        posf[w][lane][3] = nx; posf[w][lane][4] = ny; posf[w][lane][5] = nz;
        posf[w][lane][6] = rx; posf[w][lane][7] = ry; posf[w][lane][8] = rz;
        posf[w][lane][9] = dist; posf[w][lane][10] = 0.f; posf[w][lane][11] = 0.f;
    }
    const float* fT = featsT + (size_t)b * NN * C_IN;
#pragma unroll
    for (int ii = 0; ii < 2; ++ii) {
        int e4 = lane + 64 * ii;
        int k = e4 >> 3, c4 = e4 & 7;
        int idx = clampi_r26(__shfl(imv, k), 0, NN - 1);
        const float4 v = *reinterpret_cast<const float4*>(fT + (size_t)idx * C_IN + c4 * 4);
        *reinterpret_cast<float4*>(&nf[w][k][c4 * 4]) = v;
    }

    const int h = lane & 31;
    f32x2 wp2[5], wf2[16];
#pragma unroll
    for (int t = 0; t < 5; ++t)
        wp2[t] = mk2_r26(W_pos[(2 * t) * H_DIM + h], W_pos[(2 * t + 1) * H_DIM + h]);
#pragma unroll
    for (int t = 0; t < 16; ++t)
        wf2[t] = mk2_r26(W_feat[(2 * t) * H_DIM + h], W_feat[(2 * t + 1) * H_DIM + h]);
    const float bp = b_pos[h], bf = b_feat[h];

    float sP = 0.f, qP = 0.f, sF = 0.f, qF = 0.f;
    float* cp = combpre + (size_t)q * (KNB * D_DIM);
#pragma unroll
    for (int i2 = 0; i2 < 8; i2++) {
        int k = ((lane + 64 * i2) >> 5);
        float a, f;
        prebn_r26(posf[w], nf[w], k, wp2, bp, wf2, bf, &a, &f);
        sP += a; qP += a * a;
        sF += f; qF += f * f;
        cp[k * D_DIM + h] = f;
        cp[k * D_DIM + H_DIM + h] = a;
    }
    sP += __shfl_xor(sP, 32); qP += __shfl_xor(qP, 32);
    sF += __shfl_xor(sF, 32); qF += __shfl_xor(qF, 32);
    if (lane < H_DIM) {
        posS[w][h] = sP; posQ[w][h] = qP; featS[w][h] = sF; featQ[w][h] = qF;
    }
    if (lane < C_IN) {
        float s = 0.f;
#pragma unroll
        for (int k = 0; k < KNB; k++) s += nf[w][k][lane];
        meanf[w][lane] = s * (1.f / (float)KNB);
    }
    {
        float a = 0.f, c2 = 0.f;
#pragma unroll
        for (int j = 0; j < C_IN; j++) {
            a  += meanf[w][j]   * W_sc1[j * D_DIM + lane];
            c2 += centerf[w][j] * W_sc2[j * D_DIM + lane];
        }
        sc1_pre[(size_t)q * D_DIM + lane] = a;
        sc2_pre[(size_t)q * D_DIM + lane] = c2;
        s1S[w][lane] = a;  s1Q[w][lane] = a * a;
        s2S[w][lane] = c2; s2Q[w][lane] = c2 * c2;
    }
    __syncthreads();
    float* row = partialsA + (size_t)blockIdx.x * PA_W;
    if (tid < H_DIM) {
        row[SPOS_SUM + tid]  = posS[0][tid] + posS[1][tid] + posS[2][tid] + posS[3][tid];
        row[SPOS_SQ + tid]   = posQ[0][tid] + posQ[1][tid] + posQ[2][tid] + posQ[3][tid];
        row[SFEAT_SUM + tid] = featS[0][tid] + featS[1][tid] + featS[2][tid] + featS[3][tid];
        row[SFEAT_SQ + tid]  = featQ[0][tid] + featQ[1][tid] + featQ[2][tid] + featQ[3][tid];
    } else if (tid >= 64 && tid < 128) {
        int dd = tid - 64;
        row[SSC1_SUM + dd] = s1S[0][dd] + s1S[1][dd] + s1S[2][dd] + s1S[3][dd];
        row[SSC1_SQ + dd]  = s1Q[0][dd] + s1Q[1][dd] + s1Q[2][dd] + s1Q[3][dd];
    } else if (tid >= 128 && tid < 192) {
        int dd = tid - 128;
        row[SSC2_SUM + dd] = s2S[0][dd] + s2S[1][dd] + s2S[2][dd] + s2S[3][dd];
        row[SSC2_SQ + dd]  = s2Q[0][dd] + s2Q[1][dd] + s2Q[2][dd] + s2Q[3][dd];
    }
}

// ---------------- generic split reduce ----------------
#define NRSPLIT 64
__global__ __launch_bounds__(256) void reduce_r26(const float* __restrict__ partials,
                                                  int rows, int width,
                                                  float* __restrict__ stats_out) {
    const int wchunks = (width + 255) / 256;
    const int wi = blockIdx.x % wchunks;
    const int pi = blockIdx.x / wchunks;
    const int c = wi * 256 + threadIdx.x;
    if (c >= width) return;
    const int per = rows / NRSPLIT;
    const int p0 = pi * per;
    float s = 0.f;
    for (int p = p0; p < p0 + per; ++p) s += partials[(size_t)p * width + c];
    atomicAdd(&stats_out[c], s);
}

// ---------------- stage B: stream combpre -> BN -> softmax -> pooled -> W_out ----------------
__global__ __launch_bounds__(256) void stageB_r26(const float* __restrict__ combpre,
                                                  const float* __restrict__ g_pos, const float* __restrict__ be_pos,
                                                  const float* __restrict__ g_feat, const float* __restrict__ be_feat,
                                                  const float* __restrict__ W_score, const float* __restrict__ W_out,
                                                  const float* __restrict__ stats,
                                                  float* __restrict__ out_pre,
                                                  float* __restrict__ partialsB) {
    __shared__ __align__(16) float comb[4][KNB][D_DIM];
    __shared__ float scl[D_DIM], shf[D_DIM];
    __shared__ float pooled[4][D_DIM];
    __shared__ float oS[4][D_DIM], oQ[4][D_DIM];
    const int tid = threadIdx.x;
    const int w = tid >> 6, lane = tid & 63;
    const int q = blockIdx.x * 4 + w;

    if (tid < D_DIM) {
        const float inv1 = 1.f / (float)(BB * MM * KNB);
        float mean, var, g, bb;
        if (tid < H_DIM) {
            mean = stats[SFEAT_SUM + tid] * inv1;
            var  = fmaxf(stats[SFEAT_SQ + tid] * inv1 - mean * mean, 0.f);
            g = g_feat[tid]; bb = be_feat[tid];
        } else {
            int h = tid - H_DIM;
            mean = stats[SPOS_SUM + h] * inv1;
            var  = fmaxf(stats[SPOS_SQ + h] * inv1 - mean * mean, 0.f);
            g = g_pos[h]; bb = be_pos[h];
        }
        float s = g * rsqrtf(var + EPSV);
        scl[tid] = s;
        shf[tid] = bb - mean * s;
    }
    __syncthreads();

    const float4* src = reinterpret_cast<const float4*>(combpre + (size_t)blockIdx.x * 4 * KNB * D_DIM);
#pragma unroll
    for (int i = 0; i < 4; ++i) {
        int f = tid + 256 * i;
        int qloc = f >> 8;
        int k = (f >> 4) & 15;
        int j4 = f & 15;
        float4 v = src[f];
        int j = j4 * 4;
        v.x = fmaxf(v.x * scl[j + 0] + shf[j + 0], 0.f);
        v.y = fmaxf(v.y * scl[j + 1] + shf[j + 1], 0.f);
        v.z = fmaxf(v.z * scl[j + 2] + shf[j + 2], 0.f);
        v.w = fmaxf(v.w * scl[j + 3] + shf[j + 3], 0.f);
        *reinterpret_cast<float4*>(&comb[qloc][k][j]) = v;
    }
    __syncthreads();

    const int d = lane;
    f32x2 s2[KNB];
#pragma unroll
    for (int k = 0; k < KNB; k++) s2[k] = mk2_r26(0.f, 0.f);
#pragma unroll 4
    for (int j4 = 0; j4 < D_DIM / 4; ++j4) {
        f32x2 wA = mk2_r26(W_score[(j4 * 4 + 0) * D_DIM + d],
                           W_score[(j4 * 4 + 1) * D_DIM + d]);
        f32x2 wB = mk2_r26(W_score[(j4 * 4 + 2) * D_DIM + d],
                           W_score[(j4 * 4 + 3) * D_DIM + d]);
#pragma unroll
        for (int k = 0; k < KNB; k++) {
            const f32x2* cb = reinterpret_cast<const f32x2*>(&comb[w][k][j4 * 4]);
            s2[k] = cb[0] * wA + s2[k];
            s2[k] = cb[1] * wB + s2[k];
        }
    }
    float s[KNB];
#pragma unroll
    for (int k = 0; k < KNB; k++) s[k] = s2[k].x + s2[k].y;
    float mx = s[0];
#pragma unroll
    for (int k = 1; k < KNB; k++) mx = fmaxf(mx, s[k]);
    float sum = 0.f;
#pragma unroll
    for (int k = 0; k < KNB; k++) { s[k] = __expf(s[k] - mx); sum += s[k]; }
    float inv = 1.f / sum;
    float pv = 0.f;
#pragma unroll
    for (int k = 0; k < KNB; k++) pv += s[k] * inv * comb[w][k][d];
    pooled[w][d] = pv;
    __syncthreads();
    float o = 0.f;
#pragma unroll
    for (int dd = 0; dd < D_DIM; dd++) o += pooled[w][dd] * W_out[dd * D_DIM + d];
    out_pre[(size_t)q * D_DIM + d] = o;
    oS[w][d] = o; oQ[w][d] = o * o;
    __syncthreads();
    float* row = partialsB + (size_t)blockIdx.x * PB_W;
    if (tid < D_DIM) {
        row[tid] = oS[0][tid] + oS[1][tid] + oS[2][tid] + oS[3][tid];
    } else if (tid < 2 * D_DIM) {
        int dd = tid - D_DIM;
        row[D_DIM + dd] = oQ[0][dd] + oQ[1][dd] + oQ[2][dd] + oQ[3][dd];
    }
}

// ---------------- final ----------------
__global__ __launch_bounds__(256) void final_r26(const float* __restrict__ out_pre,
                                                 const float* __restrict__ sc1_pre,
                                                 const float* __restrict__ sc2_pre,
                                                 const float* __restrict__ stats,
                                                 const float* __restrict__ g_out, const float* __restrict__ be_out,
                                                 const float* __restrict__ g_sc1, const float* __restrict__ be_sc1,
                                                 const float* __restrict__ g_sc2, const float* __restrict__ be_sc2,
                                                 float* __restrict__ out) {
    __shared__ float yt[64][65];
    const int tid = threadIdx.x;
    const int blk = blockIdx.x;
    const int b = blk >> 6;
    const int m0 = (blk & 63) * 64;
    const int d = tid & 63;

    const float invn = 1.f / (float)(BB * MM);
    float mo = stats[SOUT_SUM + d] * invn;
    float vo = fmaxf(stats[SOUT_SQ + d] * invn - mo * mo, 0.f);
    float so = g_out[d] * rsqrtf(vo + EPSV);
    float oo = be_out[d] - mo * so;
    float m1 = stats[SSC1_SUM + d] * invn;
    float v1 = fmaxf(stats[SSC1_SQ + d] * invn - m1 * m1, 0.f);
    float s1 = g_sc1[d] * rsqrtf(v1 + EPSV);
    float o1 = be_sc1[d] - m1 * s1;
    float m2 = stats[SSC2_SUM + d] * invn;
    float v2 = fmaxf(stats[SSC2_SQ + d] * invn - m2 * m2, 0.f);
    float s2 = g_sc2[d] * rsqrtf(v2 + EPSV);
    float o2 = be_sc2[d] - m2 * s2;

#pragma unroll
    for (int p = 0; p < 16; p++) {
        int ml = (tid >> 6) + 4 * p;
        size_t q = (size_t)b * MM + m0 + ml;
        float x_out = fmaxf(out_pre[q * D_DIM + d] * so + oo, 0.f);
        float x1 = sc1_pre[q * D_DIM + d] * s1 + o1;
        float x2 = sc2_pre[q * D_DIM + d] * s2 + o2;
        yt[ml][d] = fmaxf(x_out + x1 + x2, 0.f);
    }
    __syncthreads();
#pragma unroll
    for (int p = 0; p < 16; p++) {
        int dr = (tid >> 6) + 4 * p;
        int mc = tid & 63;
        out[BB * MM * 3 + (size_t)b * (D_DIM * MM) + (size_t)dr * MM + m0 + mc] = yt[mc][dr];
    }
}

extern "C" void kernel_launch(void* const* d_in, const int* in_sizes, int n_in,
                              void* d_out, int out_size, void* d_ws, size_t ws_size,
                              hipStream_t stream) {
    const float* xyz        = (const float*)d_in[0];
    const float* feats      = (const float*)d_in[1];
    const int*   sample_idx = (const int*)d_in[2];
    const float* W_pos  = (const float*)d_in[3];
    const float* b_pos  = (const float*)d_in[4];
    const float* g_pos  = (const float*)d_in[5];
    const float* be_pos = (const float*)d_in[6];
    const float* W_feat  = (const float*)d_in[7];
    const float* b_feat  = (const float*)d_in[8];
    const float* g_feat  = (const float*)d_in[9];
    const float* be_feat = (const float*)d_in[10];
    const float* W_score = (const float*)d_in[11];
    const float* W_out  = (const float*)d_in[12];
    const float* g_out  = (const float*)d_in[13];
    const float* be_out = (const float*)d_in[14];
    const float* W_sc1  = (const float*)d_in[15];
    const float* g_sc1  = (const float*)d_in[16];
    const float* be_sc1 = (const float*)d_in[17];
    const float* W_sc2  = (const float*)d_in[18];
    const float* g_sc2  = (const float*)d_in[19];
    const float* be_sc2 = (const float*)d_in[20];

    float* out = (float*)d_out;
    float* ws = (float*)d_ws;

    float* featsT    = ws;                                   // 1,048,576
    float* xyz4      = featsT + 1048576;                     //   131,072
    float* sc1_pre   = xyz4 + 131072;                        //   524,288
    float* sc2_pre   = sc1_pre + 524288;                     //   524,288
    float* out_pre   = sc2_pre + 524288;                     //   524,288
    float* stats     = out_pre + 524288;                     //       512
    float* partialsA = stats + STATS_LEN;                    //   786,432
    float* partialsB = partialsA + NBLK * PA_W;              //   262,144
    int*   cand_i    = (int*)(partialsB + NBLK * PB_W);      //   131,072 ints
    int*   cellcnt   = cand_i + BB * MM * KNB;               //     1,024 ints
    int*   cellstart = cellcnt + BB * G3;                    //     1,026 ints
    int*   cursor    = cellstart + BB * (G3 + 1);            //     1,024 ints
    float* xyzr      = (float*)(cursor + BB * G3);           //   131,072 floats
    float* combpre   = xyzr + BB * NN * 4;                   // 8,388,608 (32 MB)

    prep_r26<<<BB * (NN / 64), 256, 0, stream>>>(feats, xyz, sample_idx,
                                                 featsT, xyz4, stats, cellcnt, out);

    hist_r26<<<BB * NN / 256, 256, 0, stream>>>(xyz, cellcnt);

    scan_r26<<<BB, 256, 0, stream>>>(cellcnt, cellstart, cursor);

    scatter_r26<<<BB * NN / 256, 256, 0, stream>>>(xyz, cursor, xyzr);

    knnq_r26<<<BB * MM / 4, 256, 0, stream>>>(xyz4, sample_idx, cellstart, xyzr, cand_i);

    stageA_r26<<<NBLK, 256, 0, stream>>>(xyz4, sample_idx, featsT, cand_i,
                                         W_pos, b_pos, W_feat, b_feat, W_sc1, W_sc2,
                                         combpre, sc1_pre, sc2_pre, partialsA);
    reduce_r26<<<2 * NRSPLIT, 256, 0, stream>>>(partialsA, NBLK, PA_W, stats);

    stageB_r26<<<NBLK, 256, 0, stream>>>(combpre,
                                         g_pos, be_pos, g_feat, be_feat,
                                         W_score, W_out, stats, out_pre, partialsB);
    reduce_r26<<<1 * NRSPLIT, 256, 0, stream>>>(partialsB, NBLK, PB_W, stats + SOUT_SUM);

    final_r26<<<BB * (MM / 64), 256, 0, stream>>>(out_pre, sc1_pre, sc2_pre, stats,
                                                  g_out, be_out, g_sc1, be_sc1, g_sc2, be_sc2, out);
}

// Round 12
// 231.219 us; speedup vs baseline: 3.0686x; 1.5086x over previous
//
#include <hip/hip_runtime.h>
#include <math.h>

#define BB 2
#define NN 16384
#define MM 4096
#define C_IN 32
#define D_DIM 64
#define H_DIM 32
#define KNB 16
#define EPSV 1e-5f
#define FLT_BIG 3.0e38f
#define CAPK 128
#define NSPL 4
#define SPTS (NN / NSPL)   // 4096

// stats layout (floats)
#define SPOS_SUM 0
#define SPOS_SQ 32
#define SFEAT_SUM 64
#define SFEAT_SQ 96
#define SSC1_SUM 128
#define SSC1_SQ 192
#define SSC2_SUM 256
#define SSC2_SQ 320
#define SOUT_SUM 384
#define SOUT_SQ 448
#define STATS_LEN 512
#define PA_W 384
#define PB_W 128
#define NBLK (BB * MM / 4)

typedef float f32x2 __attribute__((ext_vector_type(2)));

__device__ __forceinline__ f32x2 mk2_r28(float a, float b) {
    f32x2 r; r.x = a; r.y = b; return r;
}

__device__ __forceinline__ int clampi_r28(int v, int lo, int hi) {
    return v < lo ? lo : (v > hi ? hi : v);
}

// ---------------- prep (merged): transpose + xyz4(|p|^2) + outputs 0&2 + stats zero ----------------
__global__ __launch_bounds__(256) void prep_r28(const float* __restrict__ feats,
                                                const float* __restrict__ xyz,
                                                const int* __restrict__ sample_idx,
                                                float* __restrict__ featsT,
                                                float* __restrict__ xyz4,
                                                float* __restrict__ stats,
                                                float* __restrict__ out) {
    __shared__ float tile[C_IN][65];
    const int tid = threadIdx.x;
    const int b = blockIdx.x >> 8;
    const int n0 = (blockIdx.x & 255) * 64;
#pragma unroll
    for (int it = 0; it < 8; ++it) {
        int c = (tid >> 6) + 4 * it;
        int n = tid & 63;
        tile[c][n] = feats[((size_t)b * C_IN + c) * NN + n0 + n];
    }
    int e = blockIdx.x * 256 + tid;
    if (e < STATS_LEN) stats[e] = 0.f;
    if (e < BB * NN) {
        float x = xyz[e * 3 + 0], y = xyz[e * 3 + 1], z = xyz[e * 3 + 2];
        xyz4[e * 4 + 0] = x;
        xyz4[e * 4 + 1] = y;
        xyz4[e * 4 + 2] = z;
        xyz4[e * 4 + 3] = x * x + y * y + z * z;
    }
    if (e < BB * MM) {
        int bb2 = e >> 12;
        int sidx = clampi_r28(sample_idx[e], 0, NN - 1);
        const float* p = xyz + (size_t)(bb2 * NN + sidx) * 3;
        out[e * 3 + 0] = p[0];
        out[e * 3 + 1] = p[1];
        out[e * 3 + 2] = p[2];
        out[BB * MM * 3 + BB * D_DIM * MM + e] = (float)sample_idx[e];
    }
    __syncthreads();
#pragma unroll
    for (int it = 0; it < 8; ++it) {
        int c = tid & 31;
        int nn = (tid >> 5) + 8 * it;
        featsT[((size_t)b * NN + n0 + nn) * C_IN + c] = tile[c][nn];
    }
}

// exact full-scan fallback over one split (d2' metric) — essentially never taken
__device__ void knn_fullsplit_r28(const float* __restrict__ base4, int n0,
                                  float m2x, float m2y, float m2z, int lane,
                                  float* __restrict__ outd, int* __restrict__ outi) {
    float d2v[KNB]; int iv[KNB];
#pragma unroll
    for (int i = 0; i < KNB; i++) { d2v[i] = FLT_BIG; iv[i] = 0x7FFFFFFF; }
    float curmax = FLT_BIG; int amax = 0;
    for (int t = 0; t < SPTS / 64; ++t) {
        int n = n0 + lane + t * 64;
        const float4 p = *reinterpret_cast<const float4*>(base4 + (size_t)n * 4);
        float d2 = fmaf(p.x, m2x, p.w);
        d2 = fmaf(p.y, m2y, d2);
        d2 = fmaf(p.z, m2z, d2);
        if (d2 < curmax) {
#pragma unroll
            for (int i = 0; i < KNB; i++)
                if (i == amax) { d2v[i] = d2; iv[i] = n; }
            curmax = d2v[0]; amax = 0;
#pragma unroll
            for (int i = 1; i < KNB; i++)
                if (d2v[i] > curmax) { curmax = d2v[i]; amax = i; }
        }
    }
#pragma unroll
    for (int i = 0; i < KNB; i++) {
#pragma unroll
        for (int j = 0; j < KNB - 1; j++) {
            bool sw = (d2v[j] > d2v[j + 1]) ||
                      (d2v[j] == d2v[j + 1] && iv[j] > iv[j + 1]);
            if (sw) {
                float td = d2v[j]; d2v[j] = d2v[j + 1]; d2v[j + 1] = td;
                int   ti = iv[j];  iv[j]  = iv[j + 1];  iv[j + 1]  = ti;
            }
        }
    }
    float myd = FLT_BIG; int myidx = 0x7FFFFFFF;
#pragma unroll 1
    for (int r = 0; r < KNB; r++) {
        float cv = d2v[0]; int cid = iv[0]; int ml = lane;
#pragma unroll
        for (int off = 32; off > 0; off >>= 1) {
            float ov = __shfl_xor(cv, off);
            int   oid = __shfl_xor(cid, off);
            int   ol = __shfl_xor(ml, off);
            bool take = (ov < cv) || (ov == cv && oid < cid);
            cv = take ? ov : cv; cid = take ? oid : cid; ml = take ? ol : ml;
        }
        if (lane == r) { myd = cv; myidx = cid; }
        if (lane == ml) {
#pragma unroll
            for (int i = 0; i < KNB - 1; i++) { d2v[i] = d2v[i + 1]; iv[i] = iv[i + 1]; }
            d2v[KNB - 1] = FLT_BIG; iv[KNB - 1] = 0x7FFFFFFF;
        }
    }
    if (lane < KNB) { outd[lane] = myd; outi[lane] = myidx; }
}

// ---------------- KNN split pass (r24 form: 8 queries/wave — loads+sorts amortized 2x) ----------------
__global__ __launch_bounds__(256) void knn_r28(const float* __restrict__ xyz4,
                                               const int* __restrict__ sample_idx,
                                               float* __restrict__ cand_d,
                                               int* __restrict__ cand_i) {
    __shared__ float bufd[32][CAPK];
    __shared__ int   bufi[32][CAPK];
    const int tid = threadIdx.x;
    const int w = tid >> 6, lane = tid & 63;
    const int split = blockIdx.x & (NSPL - 1);
    const int qgrp = blockIdx.x >> 2;
    const int qbase = qgrp * 32 + w * 8;
    const int b = qbase >> 12;
    const int n0 = split * SPTS;
    const float* base4 = xyz4 + (size_t)b * NN * 4;
    const float4* p4 = reinterpret_cast<const float4*>(base4) + n0 + lane;

    float m2x[8], m2y[8], m2z[8], md[8], v16[8];
#pragma unroll
    for (int j = 0; j < 8; j++) {
        int s = clampi_r28(sample_idx[qbase + j], 0, NN - 1);
        m2x[j] = -2.f * base4[(size_t)s * 4 + 0];
        m2y[j] = -2.f * base4[(size_t)s * 4 + 1];
        m2z[j] = -2.f * base4[(size_t)s * 4 + 2];
        md[j] = FLT_BIG;
    }
    // phase 1: per-lane min of d2' over FULL split; one load feeds 8 queries
#pragma unroll 4
    for (int it = 0; it < SPTS / 64; ++it) {
        const float4 p = p4[(size_t)it * 64];
#pragma unroll
        for (int j = 0; j < 8; j++) {
            float t = fmaf(p.x, m2x[j], p.w);
            t = fmaf(p.y, m2y[j], t);
            t = fmaf(p.z, m2z[j], t);
            md[j] = fminf(md[j], t);
        }
    }
    // bound: exact 16th-smallest lane-min via 8-query-interleaved register bitonic
    // sort. >=16 points have d2' <= v16, so all true top-16 are <= v16; "<=" in
    // phase 2 keeps ties.
    {
        float sv[8];
#pragma unroll
        for (int j = 0; j < 8; j++) sv[j] = md[j];
#pragma unroll
        for (int k = 2; k <= 64; k <<= 1) {
#pragma unroll
            for (int j2 = k >> 1; j2 >= 1; j2 >>= 1) {
                const bool want_min = (((lane & j2) == 0) == ((lane & k) == 0));
#pragma unroll
                for (int j = 0; j < 8; j++) {
                    float ov = __shfl_xor(sv[j], j2);
                    float mn = fminf(sv[j], ov);
                    float mx = fmaxf(sv[j], ov);
                    sv[j] = want_min ? mn : mx;
                }
            }
        }
#pragma unroll
        for (int j = 0; j < 8; j++) v16[j] = __shfl(sv[j], KNB - 1);
    }
    // phase 2: collect candidates d2' <= bound (ballot+mbcnt compaction —
    // wave-uniform scalar counters, no LDS atomics, no block barriers)
    int cnt[8] = {0, 0, 0, 0, 0, 0, 0, 0};
#pragma unroll 4
    for (int it = 0; it < SPTS / 64; ++it) {
        const float4 p = p4[(size_t)it * 64];
        const int n = n0 + lane + it * 64;
#pragma unroll
        for (int j = 0; j < 8; j++) {
            float t = fmaf(p.x, m2x[j], p.w);
            t = fmaf(p.y, m2y[j], t);
            t = fmaf(p.z, m2z[j], t);
            bool pred = (t <= v16[j]);
            unsigned long long bal = __ballot(pred);
            if (bal) {
                int pre = __builtin_amdgcn_mbcnt_hi((unsigned)(bal >> 32),
                          __builtin_amdgcn_mbcnt_lo((unsigned)bal, 0u));
                int pos = cnt[j] + pre;
                if (pred && pos < CAPK) {
                    bufd[w * 8 + j][pos] = t;
                    bufi[w * 8 + j][pos] = n;
                }
                cnt[j] += __popcll(bal);
            }
        }
    }
    // phase 3: common case cnt<=64 -> full-wave register bitonic sort, 8 queries
    // interleaved. Fallbacks: rank loop for 64<cnt<=CAPK, exact rescan beyond.
    {
        float dv[8]; int ivv[8];
#pragma unroll
        for (int j = 0; j < 8; j++) {
            const int qi = w * 8 + j;
            bool valid = (cnt[j] <= 64) && (lane < cnt[j]);
            dv[j]  = valid ? bufd[qi][lane] : FLT_BIG;
            ivv[j] = valid ? bufi[qi][lane] : 0x7FFFFFFF;
        }
#pragma unroll
        for (int k = 2; k <= 64; k <<= 1) {
#pragma unroll
            for (int j2 = k >> 1; j2 >= 1; j2 >>= 1) {
                const bool want_min = (((lane & j2) == 0) == ((lane & k) == 0));
#pragma unroll
                for (int j = 0; j < 8; j++) {
                    float od = __shfl_xor(dv[j], j2);
                    int   oi = __shfl_xor(ivv[j], j2);
                    bool mine_less = (dv[j] < od) || (dv[j] == od && ivv[j] < oi);
                    bool keep = (mine_less == want_min);
                    dv[j]  = keep ? dv[j]  : od;
                    ivv[j] = keep ? ivv[j] : oi;
                }
            }
        }
#pragma unroll 1
        for (int j = 0; j < 8; j++) {
            const int qi = w * 8 + j;
            const int q = qbase + j;
            float* outd = cand_d + ((size_t)q * NSPL + split) * KNB;
            int*   outi = cand_i + ((size_t)q * NSPL + split) * KNB;
            if (cnt[j] <= 64) {
                if (lane < KNB) { outd[lane] = dv[j]; outi[lane] = ivv[j]; }
            } else if (cnt[j] <= CAPK) {
#pragma unroll 1
                for (int half = 0; half < 2; ++half) {
                    int i = lane + 64 * half;
                    if (i < cnt[j]) {
                        float di = bufd[qi][i]; int xi = bufi[qi][i];
                        int rank = 0;
                        for (int t = 0; t < cnt[j]; ++t) {
                            float dt = bufd[qi][t]; int xt = bufi[qi][t];
                            rank += (dt < di || (dt == di && xt < xi)) ? 1 : 0;
                        }
                        if (rank < KNB) { outd[rank] = di; outi[rank] = xi; }
                    }
                }
            } else {
                knn_fullsplit_r28(base4, n0, m2x[j], m2y[j], m2z[j], lane, outd, outi);
            }
        }
    }
}

// pre-BN pos/feat matmul for one (k,h) pair — packed-fp32 over the reduction dim
__device__ __forceinline__ void prebn_r28(const float (*posf)[12], const float (*nf)[C_IN],
                                          int k,
                                          const f32x2* __restrict__ wp2, float bp,
                                          const f32x2* __restrict__ wf2, float bf,
                                          float* a_out, float* f_out) {
    const f32x2* pp = reinterpret_cast<const f32x2*>(&posf[k][0]);
    f32x2 a2 = pp[0] * wp2[0];
    a2 = pp[1] * wp2[1] + a2;
    a2 = pp[2] * wp2[2] + a2;
    a2 = pp[3] * wp2[3] + a2;
    a2 = pp[4] * wp2[4] + a2;
    const f32x2* nn2 = reinterpret_cast<const f32x2*>(&nf[k][0]);
    f32x2 f2 = nn2[0] * wf2[0];
#pragma unroll
    for (int t = 1; t < 16; ++t) f2 = nn2[t] * wf2[t] + f2;
    *a_out = bp + a2.x + a2.y;
    *f_out = bf + f2.x + f2.y;
}

// ---------------- stage A: bitonic merge + gather + pre-BN + combpre store + partials ----------------
__global__ __launch_bounds__(256) void stageA_r28(const float* __restrict__ xyz4,
                                                  const int* __restrict__ sample_idx,
                                                  const float* __restrict__ featsT,
                                                  const float* __restrict__ cand_d,
                                                  const int* __restrict__ cand_i,
                                                  const float* __restrict__ W_pos, const float* __restrict__ b_pos,
                                                  const float* __restrict__ W_feat, const float* __restrict__ b_feat,
                                                  const float* __restrict__ W_sc1, const float* __restrict__ W_sc2,
                                                  float* __restrict__ combpre,
                                                  float* __restrict__ sc1_pre, float* __restrict__ sc2_pre,
                                                  float* __restrict__ partialsA) {
    __shared__ __align__(16) float posf[4][KNB][12];
    __shared__ __align__(16) float nf[4][KNB][C_IN];
    __shared__ float meanf[4][C_IN];
    __shared__ float centerf[4][C_IN];
    __shared__ float posS[4][H_DIM], posQ[4][H_DIM], featS[4][H_DIM], featQ[4][H_DIM];
    __shared__ float s1S[4][D_DIM], s1Q[4][D_DIM], s2S[4][D_DIM], s2Q[4][D_DIM];
    const int tid = threadIdx.x;
    const int w = tid >> 6, lane = tid & 63;
    const int q = blockIdx.x * 4 + w;
    const int b = q >> 12;
    const int sidx = clampi_r28(sample_idx[q], 0, NN - 1);
    const float* base4 = xyz4 + (size_t)b * NN * 4;

    // load 4 sorted 16-runs with odd runs reversed -> exactly the post-k=16
    // bitonic state; then run only the k=32 and k=64 merge stages (11 steps).
    float dmv; int imv;
    {
        const int run = lane >> 4, pos = lane & 15;
        const int ridx = (run & 1) ? (15 - pos) : pos;
        dmv = cand_d[(size_t)q * 64 + run * 16 + ridx];
        imv = cand_i[(size_t)q * 64 + run * 16 + ridx];
    }
    float qx = base4[(size_t)sidx * 4 + 0];
    float qy = base4[(size_t)sidx * 4 + 1];
    float qz = base4[(size_t)sidx * 4 + 2];
    if (lane < C_IN) centerf[w][lane] = featsT[((size_t)b * NN + sidx) * C_IN + lane];
#pragma unroll
    for (int k = 32; k <= 64; k <<= 1) {
#pragma unroll
        for (int j2 = k >> 1; j2 >= 1; j2 >>= 1) {
            const bool want_min = (((lane & j2) == 0) == ((lane & k) == 0));
            float od = __shfl_xor(dmv, j2);
            int   oi = __shfl_xor(imv, j2);
            bool mine_less = (dmv < od) || (dmv == od && imv < oi);
            bool keep = (mine_less == want_min);
            dmv = keep ? dmv : od;
            imv = keep ? imv : oi;
        }
    }

    if (lane < KNB) {
        int idx = clampi_r28(imv, 0, NN - 1);
        float nx = base4[(size_t)idx * 4 + 0];
        float ny = base4[(size_t)idx * 4 + 1];
        float nz = base4[(size_t)idx * 4 + 2];
        float rx = qx - nx, ry = qy - ny, rz = qz - nz;
        float dist = sqrtf(rx * rx + ry * ry + rz * rz);
        posf[w][lane][0] = qx; posf[w][lane][1] = qy; posf[w][lane][2] = qz;
        posf[w][lane][3] = nx; posf[w][lane][4] = ny; posf[w][lane][5] = nz;
        posf[w][lane][6] = rx; posf[w][lane][7] = ry; posf[w][lane][8] = rz;
        posf[w][lane][9] = dist; posf[w][lane][10] = 0.f; posf[w][lane][11] = 0.f;
    }
    const float* fT = featsT + (size_t)b * NN * C_IN;
#pragma unroll
    for (int ii = 0; ii < 2; ++ii) {
        int e4 = lane + 64 * ii;
        int k = e4 >> 3, c4 = e4 & 7;
        int idx = clampi_r28(__shfl(imv, k), 0, NN - 1);
        const float4 v = *reinterpret_cast<const float4*>(fT + (size_t)idx * C_IN + c4 * 4);
        *reinterpret_cast<float4*>(&nf[w][k][c4 * 4]) = v;
    }

    const int h = lane & 31;
    // hoisted packed weight pairs (per-thread constant: h fixed)
    f32x2 wp2[5], wf2[16];
#pragma unroll
    for (int t = 0; t < 5; ++t)
        wp2[t] = mk2_r28(W_pos[(2 * t) * H_DIM + h], W_pos[(2 * t + 1) * H_DIM + h]);
#pragma unroll
    for (int t = 0; t < 16; ++t)
        wf2[t] = mk2_r28(W_feat[(2 * t) * H_DIM + h], W_feat[(2 * t + 1) * H_DIM + h]);
    const float bp = b_pos[h], bf = b_feat[h];

    float sP = 0.f, qP = 0.f, sF = 0.f, qF = 0.f;
    float* cp = combpre + (size_t)q * (KNB * D_DIM);
#pragma unroll
    for (int i2 = 0; i2 < 8; i2++) {
        int k = ((lane + 64 * i2) >> 5);
        float a, f;
        prebn_r28(posf[w], nf[w], k, wp2, bp, wf2, bf, &a, &f);
        sP += a; qP += a * a;
        sF += f; qF += f * f;
        cp[k * D_DIM + h] = f;
        cp[k * D_DIM + H_DIM + h] = a;
    }
    sP += __shfl_xor(sP, 32); qP += __shfl_xor(qP, 32);
    sF += __shfl_xor(sF, 32); qF += __shfl_xor(qF, 32);
    if (lane < H_DIM) {
        posS[w][h] = sP; posQ[w][h] = qP; featS[w][h] = sF; featQ[w][h] = qF;
    }
    if (lane < C_IN) {
        float s = 0.f;
#pragma unroll
        for (int k = 0; k < KNB; k++) s += nf[w][k][lane];
        meanf[w][lane] = s * (1.f / (float)KNB);
    }
    {
        float a = 0.f, c2 = 0.f;
#pragma unroll
        for (int j = 0; j < C_IN; j++) {
            a  += meanf[w][j]   * W_sc1[j * D_DIM + lane];
            c2 += centerf[w][j] * W_sc2[j * D_DIM + lane];
        }
        sc1_pre[(size_t)q * D_DIM + lane] = a;
        sc2_pre[(size_t)q * D_DIM + lane] = c2;
        s1S[w][lane] = a;  s1Q[w][lane] = a * a;
        s2S[w][lane] = c2; s2Q[w][lane] = c2 * c2;
    }
    __syncthreads();
    float* row = partialsA + (size_t)blockIdx.x * PA_W;
    if (tid < H_DIM) {
        row[SPOS_SUM + tid]  = posS[0][tid] + posS[1][tid] + posS[2][tid] + posS[3][tid];
        row[SPOS_SQ + tid]   = posQ[0][tid] + posQ[1][tid] + posQ[2][tid] + posQ[3][tid];
        row[SFEAT_SUM + tid] = featS[0][tid] + featS[1][tid] + featS[2][tid] + featS[3][tid];
        row[SFEAT_SQ + tid]  = featQ[0][tid] + featQ[1][tid] + featQ[2][tid] + featQ[3][tid];
    } else if (tid >= 64 && tid < 128) {
        int dd = tid - 64;
        row[SSC1_SUM + dd] = s1S[0][dd] + s1S[1][dd] + s1S[2][dd] + s1S[3][dd];
        row[SSC1_SQ + dd]  = s1Q[0][dd] + s1Q[1][dd] + s1Q[2][dd] + s1Q[3][dd];
    } else if (tid >= 128 && tid < 192) {
        int dd = tid - 128;
        row[SSC2_SUM + dd] = s2S[0][dd] + s2S[1][dd] + s2S[2][dd] + s2S[3][dd];
        row[SSC2_SQ + dd]  = s2Q[0][dd] + s2Q[1][dd] + s2Q[2][dd] + s2Q[3][dd];
    }
}

// ---------------- generic split reduce (atomic depth per address = NRSPLIT, not NBLK) ----------------
#define NRSPLIT 64
__global__ __launch_bounds__(256) void reduce_r28(const float* __restrict__ partials,
                                                  int rows, int width,
                                                  float* __restrict__ stats_out) {
    const int wchunks = (width + 255) / 256;
    const int wi = blockIdx.x % wchunks;
    const int pi = blockIdx.x / wchunks;
    const int c = wi * 256 + threadIdx.x;
    if (c >= width) return;
    const int per = rows / NRSPLIT;
    const int p0 = pi * per;
    float s = 0.f;
    for (int p = p0; p < p0 + per; ++p) s += partials[(size_t)p * width + c];
    atomicAdd(&stats_out[c], s);
}

// ---------------- stage B: stream combpre -> BN -> softmax -> pooled -> W_out ----------------
__global__ __launch_bounds__(256) void stageB_r28(const float* __restrict__ combpre,
                                                  const float* __restrict__ g_pos, const float* __restrict__ be_pos,
                                                  const float* __restrict__ g_feat, const float* __restrict__ be_feat,
                                                  const float* __restrict__ W_score, const float* __restrict__ W_out,
                                                  const float* __restrict__ stats,
                                                  float* __restrict__ out_pre,
                                                  float* __restrict__ partialsB) {
    __shared__ __align__(16) float comb[4][KNB][D_DIM];
    __shared__ float scl[D_DIM], shf[D_DIM];
    __shared__ float pooled[4][D_DIM];
    __shared__ float oS[4][D_DIM], oQ[4][D_DIM];
    const int tid = threadIdx.x;
    const int w = tid >> 6, lane = tid & 63;
    const int q = blockIdx.x * 4 + w;

    if (tid < D_DIM) {
        const float inv1 = 1.f / (float)(BB * MM * KNB);
        float mean, var, g, bb;
        if (tid < H_DIM) {
            mean = stats[SFEAT_SUM + tid] * inv1;
            var  = fmaxf(stats[SFEAT_SQ + tid] * inv1 - mean * mean, 0.f);
            g = g_feat[tid]; bb = be_feat[tid];
        } else {
            int h = tid - H_DIM;
            mean = stats[SPOS_SUM + h] * inv1;
            var  = fmaxf(stats[SPOS_SQ + h] * inv1 - mean * mean, 0.f);
            g = g_pos[h]; bb = be_pos[h];
        }
        float s = g * rsqrtf(var + EPSV);
        scl[tid] = s;
        shf[tid] = bb - mean * s;
    }
    __syncthreads();

    const float4* src = reinterpret_cast<const float4*>(combpre + (size_t)blockIdx.x * 4 * KNB * D_DIM);
#pragma unroll
    for (int i = 0; i < 4; ++i) {
        int f = tid + 256 * i;
        int qloc = f >> 8;
        int k = (f >> 4) & 15;
        int j4 = f & 15;
        float4 v = src[f];
        int j = j4 * 4;
        v.x = fmaxf(v.x * scl[j + 0] + shf[j + 0], 0.f);
        v.y = fmaxf(v.y * scl[j + 1] + shf[j + 1], 0.f);
        v.z = fmaxf(v.z * scl[j + 2] + shf[j + 2], 0.f);
        v.w = fmaxf(v.w * scl[j + 3] + shf[j + 3], 0.f);
        *reinterpret_cast<float4*>(&comb[qloc][k][j]) = v;
    }
    __syncthreads();

    const int d = lane;
    // score matmul: packed-fp32 over the reduction dim (comb float4 halves are
    // natural f32x2 pairs; W pairs built once per j4, reused over 16 k)
    f32x2 s2[KNB];
#pragma unroll
    for (int k = 0; k < KNB; k++) s2[k] = mk2_r28(0.f, 0.f);
#pragma unroll 4
    for (int j4 = 0; j4 < D_DIM / 4; ++j4) {
        f32x2 wA = mk2_r28(W_score[(j4 * 4 + 0) * D_DIM + d],
                           W_score[(j4 * 4 + 1) * D_DIM + d]);
        f32x2 wB = mk2_r28(W_score[(j4 * 4 + 2) * D_DIM + d],
                           W_score[(j4 * 4 + 3) * D_DIM + d]);
#pragma unroll
        for (int k = 0; k < KNB; k++) {
            const f32x2* cb = reinterpret_cast<const f32x2*>(&comb[w][k][j4 * 4]);
            s2[k] = cb[0] * wA + s2[k];
            s2[k] = cb[1] * wB + s2[k];
        }
    }
    float s[KNB];
#pragma unroll
    for (int k = 0; k < KNB; k++) s[k] = s2[k].x + s2[k].y;
    float mx = s[0];
#pragma unroll
    for (int k = 1; k < KNB; k++) mx = fmaxf(mx, s[k]);
    float sum = 0.f;
#pragma unroll
    for (int k = 0; k < KNB; k++) { s[k] = __expf(s[k] - mx); sum += s[k]; }
    float inv = 1.f / sum;
    float pv = 0.f;
#pragma unroll
    for (int k = 0; k < KNB; k++) pv += s[k] * inv * comb[w][k][d];
    pooled[w][d] = pv;
    __syncthreads();
    float o = 0.f;
#pragma unroll
    for (int dd = 0; dd < D_DIM; dd++) o += pooled[w][dd] * W_out[dd * D_DIM + d];
    out_pre[(size_t)q * D_DIM + d] = o;
    oS[w][d] = o; oQ[w][d] = o * o;
    __syncthreads();
    float* row = partialsB + (size_t)blockIdx.x * PB_W;
    if (tid < D_DIM) {
        row[tid] = oS[0][tid] + oS[1][tid] + oS[2][tid] + oS[3][tid];
    } else if (tid < 2 * D_DIM) {
        int dd = tid - D_DIM;
        row[D_DIM + dd] = oQ[0][dd] + oQ[1][dd] + oQ[2][dd] + oQ[3][dd];
    }
}

// ---------------- final ----------------
__global__ __launch_bounds__(256) void final_r28(const float* __restrict__ out_pre,
                                                 const float* __restrict__ sc1_pre,
                                                 const float* __restrict__ sc2_pre,
                                                 const float* __restrict__ stats,
                                                 const float* __restrict__ g_out, const float* __restrict__ be_out,
                                                 const float* __restrict__ g_sc1, const float* __restrict__ be_sc1,
                                                 const float* __restrict__ g_sc2, const float* __restrict__ be_sc2,
                                                 float* __restrict__ out) {
    __shared__ float yt[64][65];
    const int tid = threadIdx.x;
    const int blk = blockIdx.x;
    const int b = blk >> 6;
    const int m0 = (blk & 63) * 64;
    const int d = tid & 63;

    const float invn = 1.f / (float)(BB * MM);
    float mo = stats[SOUT_SUM + d] * invn;
    float vo = fmaxf(stats[SOUT_SQ + d] * invn - mo * mo, 0.f);
    float so = g_out[d] * rsqrtf(vo + EPSV);
    float oo = be_out[d] - mo * so;
    float m1 = stats[SSC1_SUM + d] * invn;
    float v1 = fmaxf(stats[SSC1_SQ + d] * invn - m1 * m1, 0.f);
    float s1 = g_sc1[d] * rsqrtf(v1 + EPSV);
    float o1 = be_sc1[d] - m1 * s1;
    float m2 = stats[SSC2_SUM + d] * invn;
    float v2 = fmaxf(stats[SSC2_SQ + d] * invn - m2 * m2, 0.f);
    float s2 = g_sc2[d] * rsqrtf(v2 + EPSV);
    float o2 = be_sc2[d] - m2 * s2;

#pragma unroll
    for (int p = 0; p < 16; p++) {
        int ml = (tid >> 6) + 4 * p;
        size_t q = (size_t)b * MM + m0 + ml;
        float x_out = fmaxf(out_pre[q * D_DIM + d] * so + oo, 0.f);
        float x1 = sc1_pre[q * D_DIM + d] * s1 + o1;
        float x2 = sc2_pre[q * D_DIM + d] * s2 + o2;
        yt[ml][d] = fmaxf(x_out + x1 + x2, 0.f);
    }
    __syncthreads();
#pragma unroll
    for (int p = 0; p < 16; p++) {
        int dr = (tid >> 6) + 4 * p;
        int mc = tid & 63;
        out[BB * MM * 3 + (size_t)b * (D_DIM * MM) + (size_t)dr * MM + m0 + mc] = yt[mc][dr];
    }
}

extern "C" void kernel_launch(void* const* d_in, const int* in_sizes, int n_in,
                              void* d_out, int out_size, void* d_ws, size_t ws_size,
                              hipStream_t stream) {
    const float* xyz        = (const float*)d_in[0];
    const float* feats      = (const float*)d_in[1];
    const int*   sample_idx = (const int*)d_in[2];
    const float* W_pos  = (const float*)d_in[3];
    const float* b_pos  = (const float*)d_in[4];
    const float* g_pos  = (const float*)d_in[5];
    const float* be_pos = (const float*)d_in[6];
    const float* W_feat  = (const float*)d_in[7];
    const float* b_feat  = (const float*)d_in[8];
    const float* g_feat  = (const float*)d_in[9];
    const float* be_feat = (const float*)d_in[10];
    const float* W_score = (const float*)d_in[11];
    const float* W_out  = (const float*)d_in[12];
    const float* g_out  = (const float*)d_in[13];
    const float* be_out = (const float*)d_in[14];
    const float* W_sc1  = (const float*)d_in[15];
    const float* g_sc1  = (const float*)d_in[16];
    const float* be_sc1 = (const float*)d_in[17];
    const float* W_sc2  = (const float*)d_in[18];
    const float* g_sc2  = (const float*)d_in[19];
    const float* be_sc2 = (const float*)d_in[20];

    float* out = (float*)d_out;
    float* ws = (float*)d_ws;

    float* featsT    = ws;                                   // 1,048,576
    float* xyz4      = featsT + 1048576;                     //   131,072
    float* sc1_pre   = xyz4 + 131072;                        //   524,288
    float* sc2_pre   = sc1_pre + 524288;                     //   524,288
    float* out_pre   = sc2_pre + 524288;                     //   524,288
    float* stats     = out_pre + 524288;                     //       512
    float* partialsA = stats + STATS_LEN;                    //   786,432
    float* partialsB = partialsA + NBLK * PA_W;              //   262,144
    float* cand_d    = partialsB + NBLK * PB_W;              //   524,288
    int*   cand_i    = (int*)(cand_d + (size_t)BB * MM * NSPL * KNB);   // 524,288 ints
    float* combpre   = (float*)(cand_i + (size_t)BB * MM * NSPL * KNB); // 8,388,608 (32 MB)

    prep_r28<<<BB * (NN / 64), 256, 0, stream>>>(feats, xyz, sample_idx,
                                                 featsT, xyz4, stats, out);

    knn_r28<<<(BB * MM / 32) * NSPL, 256, 0, stream>>>(xyz4, sample_idx, cand_d, cand_i);

    stageA_r28<<<NBLK, 256, 0, stream>>>(xyz4, sample_idx, featsT, cand_d, cand_i,
                                         W_pos, b_pos, W_feat, b_feat, W_sc1, W_sc2,
                                         combpre, sc1_pre, sc2_pre, partialsA);
    reduce_r28<<<2 * NRSPLIT, 256, 0, stream>>>(partialsA, NBLK, PA_W, stats);

    stageB_r28<<<NBLK, 256, 0, stream>>>(combpre,
                                         g_pos, be_pos, g_feat, be_feat,
                                         W_score, W_out, stats, out_pre, partialsB);
    reduce_r28<<<1 * NRSPLIT, 256, 0, stream>>>(partialsB, NBLK, PB_W, stats + SOUT_SUM);

    final_r28<<<BB * (MM / 64), 256, 0, stream>>>(out_pre, sc1_pre, sc2_pre, stats,
                                                  g_out, be_out, g_sc1, be_sc1, g_sc2, be_sc2, out);
}